// Round 1
// baseline (530.093 us; speedup 1.0000x reference)
//
#include <hip/hip_runtime.h>
#include <stdint.h>

#define DEV __device__ __forceinline__

typedef __attribute__((ext_vector_type(8))) short bf16x8_t;   // 8 bf16 in 4 VGPRs
typedef __attribute__((ext_vector_type(4))) float f32x4_t;

DEV unsigned short f2bf(float f) {
  union { float f; uint32_t u; } x; x.f = f;
  uint32_t r = x.u + 0x7fffu + ((x.u >> 16) & 1u);
  return (unsigned short)(r >> 16);
}

// ---------------- convert fp32 -> bf16 (vectorized) ----------------
__global__ __launch_bounds__(256) void cvt_bf16_kernel(const float* __restrict__ in,
                                                       unsigned short* __restrict__ out, int n4) {
  int i = blockIdx.x * 256 + threadIdx.x;
  if (i >= n4) return;
  float4 v = reinterpret_cast<const float4*>(in)[i];
  ushort4 o;
  o.x = f2bf(v.x); o.y = f2bf(v.y); o.z = f2bf(v.z); o.w = f2bf(v.w);
  reinterpret_cast<ushort4*>(out)[i] = o;
}

// ---------------- transpose fp32 (R x C, row stride) -> bf16 (C x R) ----------------
__global__ void transpose_bf16_kernel(const float* __restrict__ in, unsigned short* __restrict__ out,
                                      int R, int C, int stride) {
  __shared__ float t[32][33];
  int bx = blockIdx.x, by = blockIdx.y;
  int tx = threadIdx.x, ty = threadIdx.y;
#pragma unroll
  for (int q = 0; q < 4; ++q) {
    int r = by * 32 + ty + q * 8, c = bx * 32 + tx;
    t[ty + q * 8][tx] = in[(size_t)r * stride + c];
  }
  __syncthreads();
#pragma unroll
  for (int q = 0; q < 4; ++q) {
    int oc = bx * 32 + ty + q * 8;
    int orr = by * 32 + tx;
    out[(size_t)oc * R + orr] = f2bf(t[tx][ty + q * 8]);
  }
}

// ---------------- bf16 MFMA GEMM:  C(MxN fp32) = A(MxK bf16) * Bt(NxK bf16)^T ----------------
__global__ __launch_bounds__(256) void gemm_bt_kernel(const unsigned short* __restrict__ A,
                                                      const unsigned short* __restrict__ Bt,
                                                      float* __restrict__ C, int K, int ldc) {
  __shared__ unsigned short As[128 * 32];
  __shared__ unsigned short Bs[128 * 32];
  int tid = threadIdx.x;
  int lane = tid & 63, wave = tid >> 6;
  int wm = wave >> 1, wn = wave & 1;
  int lr = lane & 15, lk = lane >> 4;
  long tileM = (long)blockIdx.x * 128, tileN = (long)blockIdx.y * 128;
  f32x4_t acc[4][4];
#pragma unroll
  for (int i = 0; i < 4; ++i)
#pragma unroll
    for (int j = 0; j < 4; ++j) acc[i][j] = f32x4_t{0.f, 0.f, 0.f, 0.f};

  for (int k0 = 0; k0 < K; k0 += 32) {
    __syncthreads();
    // stage A,B tiles (128x32 bf16 each = 8192B): 512 chunks of 16B, 256 threads x 2
#pragma unroll
    for (int it = 0; it < 2; ++it) {
      int lin = (tid + it * 256) * 16;  // byte offset in tile
      int row = lin >> 6, colb = lin & 63;
      bf16x8_t va = *reinterpret_cast<const bf16x8_t*>(
          (const char*)A + ((size_t)(tileM + row) * K + k0) * 2 + colb);
      bf16x8_t vb = *reinterpret_cast<const bf16x8_t*>(
          (const char*)Bt + ((size_t)(tileN + row) * K + k0) * 2 + colb);
      *reinterpret_cast<bf16x8_t*>((char*)As + lin) = va;
      *reinterpret_cast<bf16x8_t*>((char*)Bs + lin) = vb;
    }
    __syncthreads();
    bf16x8_t af[4], bfv[4];
#pragma unroll
    for (int mf = 0; mf < 4; ++mf) {
      int row = wm * 64 + mf * 16 + lr;
      af[mf] = *reinterpret_cast<const bf16x8_t*>((const char*)As + row * 64 + lk * 16);
    }
#pragma unroll
    for (int nf = 0; nf < 4; ++nf) {
      int row = wn * 64 + nf * 16 + lr;
      bfv[nf] = *reinterpret_cast<const bf16x8_t*>((const char*)Bs + row * 64 + lk * 16);
    }
#pragma unroll
    for (int mf = 0; mf < 4; ++mf)
#pragma unroll
      for (int nf = 0; nf < 4; ++nf)
        acc[mf][nf] = __builtin_amdgcn_mfma_f32_16x16x32_bf16(af[mf], bfv[nf], acc[mf][nf], 0, 0, 0);
  }
#pragma unroll
  for (int mf = 0; mf < 4; ++mf)
#pragma unroll
    for (int nf = 0; nf < 4; ++nf) {
      long r0 = tileM + wm * 64 + mf * 16 + lk * 4;
      long c0 = tileN + wn * 64 + nf * 16 + lr;
#pragma unroll
      for (int r = 0; r < 4; ++r) C[(size_t)(r0 + r) * ldc + c0] = acc[mf][nf][r];
    }
}

// ---------------- dt = softplus(u @ W_in[:,2176:2184] + dt_bias), exact fp32 ----------------
__global__ __launch_bounds__(256) void dt_kernel(const float* __restrict__ u, const float* __restrict__ W_in,
                                                 const float* __restrict__ dt_bias, float* __restrict__ dtv) {
  int row = blockIdx.x, tid = threadIdx.x;
  float ps[8] = {0.f, 0.f, 0.f, 0.f, 0.f, 0.f, 0.f, 0.f};
  const float* ur = u + (size_t)row * 1024;
#pragma unroll
  for (int kk = 0; kk < 4; ++kk) {
    int k = tid + kk * 256;
    float uv = ur[k];
    const float* wr = W_in + (size_t)k * 2184 + 2176;
#pragma unroll
    for (int h = 0; h < 8; ++h) ps[h] += uv * wr[h];
  }
#pragma unroll
  for (int h = 0; h < 8; ++h)
#pragma unroll
    for (int off = 32; off > 0; off >>= 1) ps[h] += __shfl_down(ps[h], off, 64);
  __shared__ float red[4][8];
  int lane = tid & 63, wv = tid >> 6;
  if (lane == 0) {
#pragma unroll
    for (int h = 0; h < 8; ++h) red[wv][h] = ps[h];
  }
  __syncthreads();
  if (tid < 8) {
    float s = red[0][tid] + red[1][tid] + red[2][tid] + red[3][tid] + dt_bias[tid];
    float sp = (s > 20.f) ? s : log1pf(expf(s));
    dtv[(size_t)row * 8 + tid] = sp;
  }
}

// ---------------- causal depthwise conv (width 4) + SiLU ----------------
__global__ __launch_bounds__(256) void conv_silu_kernel(const float* __restrict__ in, int in_stride,
                                                        const float* __restrict__ w, const float* __restrict__ bias,
                                                        float* __restrict__ outp, int C) {
  int idx = blockIdx.x * 256 + threadIdx.x;
  if (idx >= 8192 * C) return;
  int c = idx % C;
  int row = idx / C;
  int t = row & 4095, bb = row >> 12;
  float acc = bias[c];
  const float* wc = w + c * 4;
#pragma unroll
  for (int k = 0; k < 4; ++k) {
    int tt = t - 3 + k;
    if (tt >= 0) acc += in[(size_t)((bb << 12) + tt) * in_stride + c] * wc[k];
  }
  outp[(size_t)row * C + c] = acc / (1.f + expf(-acc));
}

// ---------------- per-chunk inclusive cumsum of dt*A ----------------
__global__ __launch_bounds__(256) void cumsum_kernel(const float* __restrict__ dtv, const float* __restrict__ Alog,
                                                     float* __restrict__ cs) {
  int blk = blockIdx.x;              // ((b*8+h)*16 + c)
  int c = blk & 15, bh = blk >> 4;
  int h = bh & 7, b = bh >> 3;
  int i = threadIdx.x;
  int row = b * 4096 + c * 256 + i;
  float A = -expf(Alog[h]);
  __shared__ float s[256];
  s[i] = dtv[(size_t)row * 8 + h] * A;
  __syncthreads();
  for (int off = 1; off < 256; off <<= 1) {
    float v = (i >= off) ? s[i - off] : 0.f;
    __syncthreads();
    s[i] += v;
    __syncthreads();
  }
  cs[(size_t)blk * 256 + i] = s[i];
}

// ---------------- chunk states: states[p,n] = sum_j B[j,n]*exp(cs_last-cs_j)*dt_j*x[j,p] ----------------
__global__ __launch_bounds__(256) void states_kernel(const float* __restrict__ xBC, const float* __restrict__ dtv,
                                                     const float* __restrict__ cs, float* __restrict__ states) {
  int blk = blockIdx.x;              // ((b*16+c)*8 + h)
  int h = blk & 7, bc = blk >> 3;
  int c = bc & 15, b = bc >> 4;
  int tid = threadIdx.x;
  int n = tid & 63, pg = tid >> 6;
  int base = b * 4096 + c * 256;
  const float* csc = cs + ((size_t)((b * 8 + h) * 16 + c)) * 256;
  __shared__ float Bs[64][64];
  __shared__ float Xs[64][128];
  __shared__ float wj[64];
  float acc[32];
#pragma unroll
  for (int q = 0; q < 32; ++q) acc[q] = 0.f;
  float cs_last = csc[255];
  for (int T = 0; T < 4; ++T) {
    __syncthreads();
    if (tid < 64) {
      int j = tid;
      wj[j] = dtv[(size_t)(base + T * 64 + j) * 8 + h] * expf(cs_last - csc[T * 64 + j]);
    }
    for (int e = tid; e < 4096; e += 256) {
      int j = e >> 6, nn = e & 63;
      Bs[j][nn] = xBC[(size_t)(base + T * 64 + j) * 1152 + 1024 + nn];
    }
    __syncthreads();
    for (int e = tid; e < 8192; e += 256) {
      int j = e >> 7, p = e & 127;
      Xs[j][p] = xBC[(size_t)(base + T * 64 + j) * 1152 + h * 128 + p] * wj[j];
    }
    __syncthreads();
    for (int j = 0; j < 64; ++j) {
      float bv = Bs[j][n];
#pragma unroll
      for (int q = 0; q < 32; ++q) acc[q] += bv * Xs[j][pg * 32 + q];
    }
  }
  float* so = states + (size_t)blk * 8192;
#pragma unroll
  for (int q = 0; q < 32; ++q) so[(size_t)(pg * 32 + q) * 64 + n] = acc[q];
}

// ---------------- sequential inter-chunk scan ----------------
__global__ __launch_bounds__(256) void scan_kernel(const float* __restrict__ states, const float* __restrict__ cs,
                                                   float* __restrict__ prev) {
  int bh = blockIdx.x;               // b*8 + h
  int h = bh & 7, b = bh >> 3;
  int tid = threadIdx.x;
  float carry[32];
#pragma unroll
  for (int i = 0; i < 32; ++i) carry[i] = 0.f;
  for (int c = 0; c < 16; ++c) {
    float d = expf(cs[((size_t)bh * 16 + c) * 256 + 255]);
    size_t off = ((size_t)(b * 16 + c) * 8 + h) * 8192;
#pragma unroll
    for (int i = 0; i < 32; ++i) {
      int e = tid + 256 * i;
      float pv = carry[i];
      prev[off + e] = pv;
      carry[i] = states[off + e] + d * pv;
    }
  }
}

// ---------------- scores: S[i,j] = (j<=i) ? (C_i . B_j) * exp(cs_i - cs_j) : 0 ----------------
__global__ __launch_bounds__(256) void scores_kernel(const float* __restrict__ xBC, const float* __restrict__ cs,
                                                     float* __restrict__ S) {
  int blk = blockIdx.x;
  int jt = blk & 3, it = (blk >> 2) & 3;
  if (jt > it) return;               // strictly-upper tiles never read
  int bch = blk >> 4;
  int h = bch & 7, bc = bch >> 3, c = bc & 15, b = bc >> 4;
  int tid = threadIdx.x, tj = tid & 15, ti = tid >> 4;
  int base = b * 4096 + c * 256;
  const float* csc = cs + ((size_t)((b * 8 + h) * 16 + c)) * 256;
  __shared__ float Csh[64][65], Bsh[64][65];
  int i0 = it * 64, j0 = jt * 64;
  for (int e = tid; e < 4096; e += 256) {
    int r = e >> 6, nn = e & 63;
    Csh[r][nn] = xBC[(size_t)(base + i0 + r) * 1152 + 1088 + nn];
    Bsh[r][nn] = xBC[(size_t)(base + j0 + r) * 1152 + 1024 + nn];
  }
  __syncthreads();
  float acc[4][4] = {};
  for (int nn = 0; nn < 64; ++nn) {
    float cv[4], bv[4];
#pragma unroll
    for (int a = 0; a < 4; ++a) cv[a] = Csh[ti * 4 + a][nn];
#pragma unroll
    for (int bq = 0; bq < 4; ++bq) bv[bq] = Bsh[tj * 4 + bq][nn];
#pragma unroll
    for (int a = 0; a < 4; ++a)
#pragma unroll
      for (int bq = 0; bq < 4; ++bq) acc[a][bq] += cv[a] * bv[bq];
  }
  float* Sp = S + (size_t)bch * 65536;
#pragma unroll
  for (int a = 0; a < 4; ++a) {
    int i = i0 + ti * 4 + a;
    float csi = csc[i];
#pragma unroll
    for (int bq = 0; bq < 4; ++bq) {
      int j = j0 + tj * 4 + bq;
      float v = (j <= i) ? acc[a][bq] * expf(csi - csc[j]) : 0.f;
      Sp[(size_t)i * 256 + j] = v;
    }
  }
}

// ---------------- Y = S@X + (C*exp(cs))@prev^T + D*x ----------------
__global__ __launch_bounds__(256) void y_kernel(const float* __restrict__ S, const float* __restrict__ xBC,
                                                const float* __restrict__ dtv, const float* __restrict__ cs,
                                                const float* __restrict__ prev, const float* __restrict__ Dp,
                                                float* __restrict__ y) {
  int blk = blockIdx.x;
  int it = blk & 3;
  int bch = blk >> 2;
  int h = bch & 7, bc = bch >> 3, c = bc & 15, b = bc >> 4;
  int tid = threadIdx.x;
  int pl = tid & 31, ig = tid >> 5;
  int base = b * 4096 + c * 256, i0 = it * 64;
  const float* csc = cs + ((size_t)((b * 8 + h) * 16 + c)) * 256;
  __shared__ float Ss[64][65];
  __shared__ float Xls[64][129];
  float acc[8][4] = {};
  const float* Sp = S + (size_t)bch * 65536;
  for (int jt = 0; jt <= it; ++jt) {
    __syncthreads();
    for (int e = tid; e < 4096; e += 256) {
      int ii = e >> 6, jj = e & 63;
      Ss[ii][jj] = Sp[(size_t)(i0 + ii) * 256 + jt * 64 + jj];
    }
    for (int e = tid; e < 8192; e += 256) {
      int j = e >> 7, p = e & 127;
      int row = base + jt * 64 + j;
      Xls[j][p] = xBC[(size_t)row * 1152 + h * 128 + p] * dtv[(size_t)row * 8 + h];
    }
    __syncthreads();
    for (int j = 0; j < 64; ++j) {
      float xv[4];
#pragma unroll
      for (int pb = 0; pb < 4; ++pb) xv[pb] = Xls[j][pl + 32 * pb];
#pragma unroll
      for (int aa = 0; aa < 8; ++aa) {
        float sv = Ss[ig + 8 * aa][j];
#pragma unroll
        for (int pb = 0; pb < 4; ++pb) acc[aa][pb] += sv * xv[pb];
      }
    }
  }
  __syncthreads();
  // stage C*exp(cs_i) into Ss, prev^T into Xls
  for (int e = tid; e < 4096; e += 256) {
    int ii = e >> 6, nn = e & 63;
    Ss[ii][nn] = xBC[(size_t)(base + i0 + ii) * 1152 + 1088 + nn] * expf(csc[i0 + ii]);
  }
  for (int e = tid; e < 8192; e += 256) {
    int nn = e & 63, p = e >> 6;
    Xls[nn][p] = prev[(size_t)bch * 8192 + (size_t)p * 64 + nn];
  }
  __syncthreads();
  for (int nn = 0; nn < 64; ++nn) {
    float pv[4];
#pragma unroll
    for (int pb = 0; pb < 4; ++pb) pv[pb] = Xls[nn][pl + 32 * pb];
#pragma unroll
    for (int aa = 0; aa < 8; ++aa) {
      float cv = Ss[ig + 8 * aa][nn];
#pragma unroll
      for (int pb = 0; pb < 4; ++pb) acc[aa][pb] += cv * pv[pb];
    }
  }
  float Dh = Dp[h];
#pragma unroll
  for (int aa = 0; aa < 8; ++aa) {
    int i = i0 + ig + 8 * aa;
    int row = base + i;
#pragma unroll
    for (int pb = 0; pb < 4; ++pb) {
      int p = pl + 32 * pb;
      float xraw = xBC[(size_t)row * 1152 + h * 128 + p];
      y[(size_t)row * 1024 + h * 128 + p] = acc[aa][pb] + Dh * xraw;
    }
  }
}

// ---------------- RMSNorm over concat(y, z) -> bf16 ----------------
__global__ __launch_bounds__(256) void rmsnorm_kernel(const float* __restrict__ y, const float* __restrict__ z,
                                                      const float* __restrict__ nw, unsigned short* __restrict__ out) {
  int row = blockIdx.x, tid = threadIdx.x;
  float4 a = reinterpret_cast<const float4*>(y + (size_t)row * 1024)[tid];
  float4 bv = reinterpret_cast<const float4*>(z + (size_t)row * 1024)[tid];
  float ss = a.x * a.x + a.y * a.y + a.z * a.z + a.w * a.w +
             bv.x * bv.x + bv.y * bv.y + bv.z * bv.z + bv.w * bv.w;
#pragma unroll
  for (int off = 32; off > 0; off >>= 1) ss += __shfl_down(ss, off, 64);
  __shared__ float red[4];
  __shared__ float stot;
  int lane = tid & 63, wv = tid >> 6;
  if (lane == 0) red[wv] = ss;
  __syncthreads();
  if (tid == 0) stot = rsqrtf((red[0] + red[1] + red[2] + red[3]) * (1.f / 2048.f) + 1e-5f);
  __syncthreads();
  float s = stot;
  float4 w1 = reinterpret_cast<const float4*>(nw)[tid];
  float4 w2 = reinterpret_cast<const float4*>(nw + 1024)[tid];
  ushort4 o1, o2;
  o1.x = f2bf(a.x * s * w1.x); o1.y = f2bf(a.y * s * w1.y);
  o1.z = f2bf(a.z * s * w1.z); o1.w = f2bf(a.w * s * w1.w);
  o2.x = f2bf(bv.x * s * w2.x); o2.y = f2bf(bv.y * s * w2.y);
  o2.z = f2bf(bv.z * s * w2.z); o2.w = f2bf(bv.w * s * w2.w);
  reinterpret_cast<ushort4*>(out + (size_t)row * 2048)[tid] = o1;
  reinterpret_cast<ushort4*>(out + (size_t)row * 2048 + 1024)[tid] = o2;
}

extern "C" void kernel_launch(void* const* d_in, const int* in_sizes, int n_in,
                              void* d_out, int out_size, void* d_ws, size_t ws_size,
                              hipStream_t stream) {
  const float* u       = (const float*)d_in[0];
  const float* W_in    = (const float*)d_in[1];
  const float* xconv_w = (const float*)d_in[2];
  const float* xconv_b = (const float*)d_in[3];
  const float* zconv_w = (const float*)d_in[4];
  const float* zconv_b = (const float*)d_in[5];
  const float* dt_bias = (const float*)d_in[6];
  const float* Alog    = (const float*)d_in[7];
  const float* Dp      = (const float*)d_in[8];
  const float* norm_w  = (const float*)d_in[9];
  const float* W_out   = (const float*)d_in[10];
  float* out = (float*)d_out;

  char* ws = (char*)d_ws;
  size_t o = 0;
  auto alc = [&](size_t bytes) { void* p = (void*)(ws + o); o = (o + bytes + 255) & ~(size_t)255; return p; };
  unsigned short* A1   = (unsigned short*)alc(16777216);   // u in bf16 (8192x1024)
  unsigned short* Wt1  = (unsigned short*)alc(4456448);    // W_in^T cols 0..2175 (2176x1024)
  unsigned short* Wt2  = (unsigned short*)alc(4194304);    // W_out^T (1024x2048)
  char* R1 = (char*)alc(71303168);                         // zxbcdt -> scores -> normed (lifetimes disjoint)
  float* zx = (float*)R1;                                  // 8192 x 2176
  float* Sbuf = (float*)R1;                                // 256 x 256 x 256
  unsigned short* normed = (unsigned short*)R1;            // 8192 x 2048 bf16
  float* dtv   = (float*)alc(262144);                      // 8192 x 8
  float* csb   = (float*)alc(262144);                      // [b][h][c][256]
  float* xBC   = (float*)alc(37748736);                    // 8192 x 1152
  float* zc    = (float*)alc(33554432);                    // 8192 x 1024
  float* stat  = (float*)alc(8388608);                     // [b][c][h][128][64]
  float* prevb = (float*)alc(8388608);
  float* yb    = (float*)alc(33554432);                    // 8192 x 1024
  (void)ws_size; (void)in_sizes; (void)n_in; (void)out_size;

  dim3 tb(32, 8);
  cvt_bf16_kernel<<<8192, 256, 0, stream>>>(u, A1, 2097152);
  transpose_bf16_kernel<<<dim3(68, 32), tb, 0, stream>>>(W_in, Wt1, 1024, 2176, 2184);
  transpose_bf16_kernel<<<dim3(32, 64), tb, 0, stream>>>(W_out, Wt2, 2048, 1024, 1024);
  gemm_bt_kernel<<<dim3(64, 17), 256, 0, stream>>>(A1, Wt1, zx, 1024, 2176);
  dt_kernel<<<8192, 256, 0, stream>>>(u, W_in, dt_bias, dtv);
  conv_silu_kernel<<<36864, 256, 0, stream>>>(zx + 1024, 2176, xconv_w, xconv_b, xBC, 1152);
  conv_silu_kernel<<<32768, 256, 0, stream>>>(zx, 2176, zconv_w, zconv_b, zc, 1024);
  cumsum_kernel<<<256, 256, 0, stream>>>(dtv, Alog, csb);
  states_kernel<<<256, 256, 0, stream>>>(xBC, dtv, csb, stat);
  scan_kernel<<<16, 256, 0, stream>>>(stat, csb, prevb);
  scores_kernel<<<4096, 256, 0, stream>>>(xBC, csb, Sbuf);
  y_kernel<<<1024, 256, 0, stream>>>(Sbuf, xBC, dtv, csb, prevb, Dp, yb);
  rmsnorm_kernel<<<8192, 256, 0, stream>>>(yb, zc, norm_w, normed);
  gemm_bt_kernel<<<dim3(64, 8), 256, 0, stream>>>(normed, Wt2, out, 2048, 1024);
}

// Round 2
// 450.811 us; speedup vs baseline: 1.1759x; 1.1759x over previous
//
#include <hip/hip_runtime.h>
#include <stdint.h>

#define DEV __device__ __forceinline__

typedef __attribute__((ext_vector_type(8))) short bf16x8_t;   // 8 bf16 in 4 VGPRs
typedef __attribute__((ext_vector_type(4))) float f32x4_t;

DEV unsigned short f2bf(float f) {
  union { float f; uint32_t u; } x; x.f = f;
  uint32_t r = x.u + 0x7fffu + ((x.u >> 16) & 1u);
  return (unsigned short)(r >> 16);
}
DEV float bf2f(unsigned short u) {
  union { uint32_t u; float f; } x; x.u = ((uint32_t)u) << 16;
  return x.f;
}

#define GLOAD_LDS16(g, l)                                                              \
  __builtin_amdgcn_global_load_lds((const __attribute__((address_space(1))) unsigned int*)(g), \
                                   (__attribute__((address_space(3))) unsigned int*)(l), 16, 0, 0)

// ---------------- convert fp32 -> bf16 (vectorized) ----------------
__global__ __launch_bounds__(256) void cvt_bf16_kernel(const float* __restrict__ in,
                                                       unsigned short* __restrict__ out, int n4) {
  int i = blockIdx.x * 256 + threadIdx.x;
  if (i >= n4) return;
  float4 v = reinterpret_cast<const float4*>(in)[i];
  ushort4 o;
  o.x = f2bf(v.x); o.y = f2bf(v.y); o.z = f2bf(v.z); o.w = f2bf(v.w);
  reinterpret_cast<ushort4*>(out)[i] = o;
}

// ---------------- transpose fp32 (R x C, row stride) -> bf16 (C x R) ----------------
__global__ void transpose_bf16_kernel(const float* __restrict__ in, unsigned short* __restrict__ out,
                                      int R, int C, int stride) {
  __shared__ float t[32][33];
  int bx = blockIdx.x, by = blockIdx.y;
  int tx = threadIdx.x, ty = threadIdx.y;
#pragma unroll
  for (int q = 0; q < 4; ++q) {
    int r = by * 32 + ty + q * 8, c = bx * 32 + tx;
    t[ty + q * 8][tx] = in[(size_t)r * stride + c];
  }
  __syncthreads();
#pragma unroll
  for (int q = 0; q < 4; ++q) {
    int oc = bx * 32 + ty + q * 8;
    int orr = by * 32 + tx;
    out[(size_t)oc * R + orr] = f2bf(t[tx][ty + q * 8]);
  }
}

// ---------------- bf16 MFMA GEMM with global_load_lds staging ----------------
// C(MxN) = A(MxK bf16) * Bt(NxK bf16)^T ; OBF: output bf16 else fp32
template <int OBF>
__global__ __launch_bounds__(256) void gemm_bt_kernel(const unsigned short* __restrict__ A,
                                                      const unsigned short* __restrict__ Bt,
                                                      void* __restrict__ Cout, int K, int ldc) {
  __shared__ __align__(16) unsigned short As[128 * 32];
  __shared__ __align__(16) unsigned short Bs[128 * 32];
  int tid = threadIdx.x;
  int lane = tid & 63, wave = tid >> 6;
  int wm = wave >> 1, wn = wave & 1;
  int lr = lane & 15, lk = lane >> 4;
  long tileM = (long)blockIdx.x * 128, tileN = (long)blockIdx.y * 128;
  f32x4_t acc[4][4];
#pragma unroll
  for (int i = 0; i < 4; ++i)
#pragma unroll
    for (int j = 0; j < 4; ++j) acc[i][j] = f32x4_t{0.f, 0.f, 0.f, 0.f};

  for (int k0 = 0; k0 < K; k0 += 32) {
    __syncthreads();
#pragma unroll
    for (int it = 0; it < 2; ++it) {
      int chunk = (it * 4 + wave) * 64 + lane;   // 0..511, 16B each
      int row = chunk >> 2;
      int kb = (chunk & 3) * 8;                  // elem offset
      unsigned int ldsoff = (unsigned int)((it * 4 + wave) * 1024);  // bytes, wave-uniform
      GLOAD_LDS16(A + (size_t)(tileM + row) * K + k0 + kb, (char*)As + ldsoff);
      GLOAD_LDS16(Bt + (size_t)(tileN + row) * K + k0 + kb, (char*)Bs + ldsoff);
    }
    __syncthreads();
    bf16x8_t af[4], bfv[4];
#pragma unroll
    for (int mf = 0; mf < 4; ++mf) {
      int row = wm * 64 + mf * 16 + lr;
      af[mf] = *reinterpret_cast<const bf16x8_t*>((const char*)As + row * 64 + lk * 16);
    }
#pragma unroll
    for (int nf = 0; nf < 4; ++nf) {
      int row = wn * 64 + nf * 16 + lr;
      bfv[nf] = *reinterpret_cast<const bf16x8_t*>((const char*)Bs + row * 64 + lk * 16);
    }
#pragma unroll
    for (int mf = 0; mf < 4; ++mf)
#pragma unroll
      for (int nf = 0; nf < 4; ++nf)
        acc[mf][nf] = __builtin_amdgcn_mfma_f32_16x16x32_bf16(af[mf], bfv[nf], acc[mf][nf], 0, 0, 0);
  }
#pragma unroll
  for (int mf = 0; mf < 4; ++mf)
#pragma unroll
    for (int nf = 0; nf < 4; ++nf) {
      long r0 = tileM + wm * 64 + mf * 16 + lk * 4;
      long c0 = tileN + wn * 64 + nf * 16 + lr;
#pragma unroll
      for (int r = 0; r < 4; ++r) {
        if (OBF)
          ((unsigned short*)Cout)[(size_t)(r0 + r) * ldc + c0] = f2bf(acc[mf][nf][r]);
        else
          ((float*)Cout)[(size_t)(r0 + r) * ldc + c0] = acc[mf][nf][r];
      }
    }
}

// ---------------- dt = softplus(u @ W_in[:,2176:2184] + dt_bias), exact fp32 ----------------
__global__ __launch_bounds__(256) void dt_kernel(const float* __restrict__ u, const float* __restrict__ W_in,
                                                 const float* __restrict__ dt_bias, float* __restrict__ dtv) {
  int row = blockIdx.x, tid = threadIdx.x;
  float ps[8] = {0.f, 0.f, 0.f, 0.f, 0.f, 0.f, 0.f, 0.f};
  const float* ur = u + (size_t)row * 1024;
#pragma unroll
  for (int kk = 0; kk < 4; ++kk) {
    int k = tid + kk * 256;
    float uv = ur[k];
    const float* wr = W_in + (size_t)k * 2184 + 2176;
#pragma unroll
    for (int h = 0; h < 8; ++h) ps[h] += uv * wr[h];
  }
#pragma unroll
  for (int h = 0; h < 8; ++h)
#pragma unroll
    for (int off = 32; off > 0; off >>= 1) ps[h] += __shfl_down(ps[h], off, 64);
  __shared__ float red[4][8];
  int lane = tid & 63, wv = tid >> 6;
  if (lane == 0) {
#pragma unroll
    for (int h = 0; h < 8; ++h) red[wv][h] = ps[h];
  }
  __syncthreads();
  if (tid < 8) {
    float s = red[0][tid] + red[1][tid] + red[2][tid] + red[3][tid] + dt_bias[tid];
    float sp = (s > 20.f) ? s : log1pf(expf(s));
    dtv[(size_t)row * 8 + tid] = sp;
  }
}

// ---------------- causal depthwise conv (width 4) + SiLU, bf16 in/out, 2 ch/thread ----------------
__global__ __launch_bounds__(256) void conv_silu_kernel(const unsigned short* __restrict__ in, int in_stride,
                                                        const float* __restrict__ w, const float* __restrict__ bias,
                                                        unsigned short* __restrict__ outp, int C) {
  int C2 = C >> 1;
  int idx = blockIdx.x * 256 + threadIdx.x;
  if (idx >= 8192 * C2) return;
  int c2 = idx % C2;
  int row = idx / C2;
  int c = c2 * 2;
  int t = row & 4095, bb = row >> 12;
  float a0 = bias[c], a1 = bias[c + 1];
#pragma unroll
  for (int k = 0; k < 4; ++k) {
    int tt = t - 3 + k;
    if (tt >= 0) {
      unsigned int v = *reinterpret_cast<const unsigned int*>(in + (size_t)((bb << 12) + tt) * in_stride + c);
      a0 += bf2f((unsigned short)(v & 0xffffu)) * w[c * 4 + k];
      a1 += bf2f((unsigned short)(v >> 16)) * w[(c + 1) * 4 + k];
    }
  }
  a0 = a0 / (1.f + expf(-a0));
  a1 = a1 / (1.f + expf(-a1));
  unsigned int o = (unsigned int)f2bf(a0) | ((unsigned int)f2bf(a1) << 16);
  *reinterpret_cast<unsigned int*>(outp + (size_t)row * C + c) = o;
}

// ---------------- per-chunk inclusive cumsum of dt*A ----------------
__global__ __launch_bounds__(256) void cumsum_kernel(const float* __restrict__ dtv, const float* __restrict__ Alog,
                                                     float* __restrict__ cs) {
  int blk = blockIdx.x;              // ((b*8+h)*16 + c)
  int c = blk & 15, bh = blk >> 4;
  int h = bh & 7, b = bh >> 3;
  int i = threadIdx.x;
  int row = b * 4096 + c * 256 + i;
  float A = -expf(Alog[h]);
  __shared__ float s[256];
  s[i] = dtv[(size_t)row * 8 + h] * A;
  __syncthreads();
  for (int off = 1; off < 256; off <<= 1) {
    float v = (i >= off) ? s[i - off] : 0.f;
    __syncthreads();
    s[i] += v;
    __syncthreads();
  }
  cs[(size_t)blk * 256 + i] = s[i];
}

// ---------------- chunk states via MFMA: states[p,n] = sum_j B[j,n]*exp(csl-cs_j)*dt_j*x[j,p] ----------------
// grid: ((b*16+c)*8+h)*2 + ph  (512 blocks)
__global__ __launch_bounds__(256) void states_mfma_kernel(const unsigned short* __restrict__ xBC,
                                                          const float* __restrict__ dtv,
                                                          const float* __restrict__ cs,
                                                          float* __restrict__ states) {
  int blk = blockIdx.x;
  int ph = blk & 1, bch = blk >> 1;
  int h = bch & 7, bc = bch >> 3, c = bc & 15, b = bc >> 4;
  int tid = threadIdx.x, lane = tid & 63, wv = tid >> 6;
  int lr = lane & 15, lk = lane >> 4;
  int base = b * 4096 + c * 256;
  __shared__ __align__(16) unsigned short Xt[64 * 264];  // [p][j] pad->264
  __shared__ __align__(16) unsigned short Bw[64 * 264];  // [n][j]
  __shared__ float csc[256], wj[256];
  csc[tid] = cs[((size_t)((b * 8 + h) * 16 + c)) * 256 + tid];
  __syncthreads();
  float csl = csc[255];
  wj[tid] = dtv[(size_t)(base + tid) * 8 + h] * expf(csl - csc[tid]);
  __syncthreads();
  {
    int grp = tid >> 6;
    for (int j = grp; j < 256; j += 4) {
      size_t row = (size_t)(base + j) * 1152;
      float xv = bf2f(xBC[row + h * 128 + ph * 64 + lane]) * wj[j];
      Xt[lane * 264 + j] = f2bf(xv);
      Bw[lane * 264 + j] = xBC[row + 1024 + lane];
    }
  }
  __syncthreads();
  f32x4_t acc[4];
#pragma unroll
  for (int nf = 0; nf < 4; ++nf) acc[nf] = f32x4_t{0.f, 0.f, 0.f, 0.f};
  for (int ks = 0; ks < 8; ++ks) {
    bf16x8_t af = *reinterpret_cast<const bf16x8_t*>(Xt + (wv * 16 + lr) * 264 + ks * 32 + lk * 8);
#pragma unroll
    for (int nf = 0; nf < 4; ++nf) {
      bf16x8_t bfr = *reinterpret_cast<const bf16x8_t*>(Bw + (nf * 16 + lr) * 264 + ks * 32 + lk * 8);
      acc[nf] = __builtin_amdgcn_mfma_f32_16x16x32_bf16(af, bfr, acc[nf], 0, 0, 0);
    }
  }
  float* so = states + (size_t)bch * 8192;
#pragma unroll
  for (int nf = 0; nf < 4; ++nf)
#pragma unroll
    for (int r = 0; r < 4; ++r)
      so[(size_t)(ph * 64 + wv * 16 + lk * 4 + r) * 64 + nf * 16 + lr] = acc[nf][r];
}

// ---------------- sequential inter-chunk scan (fp32) ----------------
__global__ __launch_bounds__(256) void scan_kernel(const float* __restrict__ states, const float* __restrict__ cs,
                                                   float* __restrict__ prev) {
  int bh = blockIdx.x;               // b*8 + h
  int h = bh & 7, b = bh >> 3;
  int tid = threadIdx.x;
  float carry[32];
#pragma unroll
  for (int i = 0; i < 32; ++i) carry[i] = 0.f;
  for (int c = 0; c < 16; ++c) {
    float d = expf(cs[((size_t)bh * 16 + c) * 256 + 255]);
    size_t off = ((size_t)(b * 16 + c) * 8 + h) * 8192;
#pragma unroll
    for (int i = 0; i < 32; ++i) {
      int e = tid + 256 * i;
      float pv = carry[i];
      prev[off + e] = pv;
      carry[i] = states[off + e] + d * pv;
    }
  }
}

// ---------------- fused scores+Y: Y = mask(CB^T . exp(seg)) @ (dt x) + (C e^cs) @ prev^T + D x ----------------
// grid: bch*2 + ph (512 blocks), 256 threads, wave wv owns rows i in [wv*64, wv*64+64)
__global__ __launch_bounds__(256) void fused_y_kernel(const unsigned short* __restrict__ xBC,
                                                      const float* __restrict__ dtv,
                                                      const float* __restrict__ cs,
                                                      const float* __restrict__ prevb,
                                                      const float* __restrict__ Dp,
                                                      unsigned short* __restrict__ yb) {
  int blk = blockIdx.x;
  int ph = blk & 1, bch = blk >> 1;
  int h = bch & 7, bc = bch >> 3, c = bc & 15, b = bc >> 4;
  int tid = threadIdx.x, lane = tid & 63, wv = tid >> 6;
  int lr = lane & 15, lk = lane >> 4;
  int base = b * 4096 + c * 256;
  __shared__ __align__(16) unsigned short Bst[64 * 72];   // [j][n]
  __shared__ __align__(16) unsigned short Xtt[64 * 72];   // [p][j]
  __shared__ __align__(16) unsigned short prevs[64 * 72]; // [p][n]
  __shared__ __align__(16) unsigned short Ss[4][64 * 72]; // per-wave S tile [i][j]
  __shared__ float csc[256], dtw[256];

  csc[tid] = cs[((size_t)((b * 8 + h) * 16 + c)) * 256 + tid];
  dtw[tid] = dtv[(size_t)(base + tid) * 8 + h];
  for (int e = tid; e < 4096; e += 256) {
    int p = e >> 6, n = e & 63;
    prevs[p * 72 + n] = f2bf(prevb[(size_t)bch * 8192 + (size_t)(ph * 64 + p) * 64 + n]);
  }
  __syncthreads();

  // C fragments (A-operand rows i = wv*64 + mf*16 + lr) straight from global bf16
  bf16x8_t cf[4][2], cdf[4][2];
#pragma unroll
  for (int mf = 0; mf < 4; ++mf) {
    int iloc = wv * 64 + mf * 16 + lr;
    size_t row = (size_t)(base + iloc) * 1152;
    float sc = expf(csc[iloc]);
#pragma unroll
    for (int ks = 0; ks < 2; ++ks) {
      bf16x8_t v = *reinterpret_cast<const bf16x8_t*>(xBC + row + 1088 + ks * 32 + lk * 8);
      cf[mf][ks] = v;
      bf16x8_t d;
#pragma unroll
      for (int e = 0; e < 8; ++e) d[e] = (short)f2bf(bf2f((unsigned short)v[e]) * sc);
      cdf[mf][ks] = d;
    }
  }

  // acc starts as Y_off = Cd @ prev^T
  f32x4_t acc[4][4];
#pragma unroll
  for (int mf = 0; mf < 4; ++mf)
#pragma unroll
    for (int nf = 0; nf < 4; ++nf) acc[mf][nf] = f32x4_t{0.f, 0.f, 0.f, 0.f};
#pragma unroll
  for (int ks = 0; ks < 2; ++ks) {
    bf16x8_t pf[4];
#pragma unroll
    for (int nf = 0; nf < 4; ++nf)
      pf[nf] = *reinterpret_cast<const bf16x8_t*>(prevs + (nf * 16 + lr) * 72 + ks * 32 + lk * 8);
#pragma unroll
    for (int mf = 0; mf < 4; ++mf)
#pragma unroll
      for (int nf = 0; nf < 4; ++nf)
        acc[mf][nf] = __builtin_amdgcn_mfma_f32_16x16x32_bf16(cdf[mf][ks], pf[nf], acc[mf][nf], 0, 0, 0);
  }

  for (int jt = 0; jt < 4; ++jt) {
    __syncthreads();
    {
      int grp = tid >> 6;
      for (int j = grp; j < 64; j += 4) {
        size_t row = (size_t)(base + jt * 64 + j) * 1152;
        Bst[j * 72 + lane] = xBC[row + 1024 + lane];
        float xv = bf2f(xBC[row + h * 128 + ph * 64 + lane]) * dtw[jt * 64 + j];
        Xtt[lane * 72 + j] = f2bf(xv);
      }
    }
    __syncthreads();
    if (jt <= wv) {
      f32x4_t s[4][4];
#pragma unroll
      for (int mf = 0; mf < 4; ++mf)
#pragma unroll
        for (int jf = 0; jf < 4; ++jf) s[mf][jf] = f32x4_t{0.f, 0.f, 0.f, 0.f};
#pragma unroll
      for (int ks = 0; ks < 2; ++ks) {
        bf16x8_t bfr[4];
#pragma unroll
        for (int jf = 0; jf < 4; ++jf)
          bfr[jf] = *reinterpret_cast<const bf16x8_t*>(Bst + (jf * 16 + lr) * 72 + ks * 32 + lk * 8);
#pragma unroll
        for (int mf = 0; mf < 4; ++mf)
#pragma unroll
          for (int jf = 0; jf < 4; ++jf)
            s[mf][jf] = __builtin_amdgcn_mfma_f32_16x16x32_bf16(cf[mf][ks], bfr[jf], s[mf][jf], 0, 0, 0);
      }
      // decay + mask -> bf16 S tile in LDS (A layout [i][j])
#pragma unroll
      for (int mf = 0; mf < 4; ++mf) {
        float csi[4];
#pragma unroll
        for (int r = 0; r < 4; ++r) csi[r] = csc[wv * 64 + mf * 16 + lk * 4 + r];
#pragma unroll
        for (int jf = 0; jf < 4; ++jf) {
          int jloc = jf * 16 + lr;
          int jg = jt * 64 + jloc;
          float csj = csc[jg];
#pragma unroll
          for (int r = 0; r < 4; ++r) {
            int i = wv * 64 + mf * 16 + lk * 4 + r;
            float w = (jg <= i) ? expf(csi[r] - csj) : 0.f;
            Ss[wv][(mf * 16 + lk * 4 + r) * 72 + jloc] = f2bf(s[mf][jf][r] * w);
          }
        }
      }
    }
    __syncthreads();
    if (jt <= wv) {
#pragma unroll
      for (int ks = 0; ks < 2; ++ks) {
        bf16x8_t afr[4], xfr[4];
#pragma unroll
        for (int mf = 0; mf < 4; ++mf)
          afr[mf] = *reinterpret_cast<const bf16x8_t*>(&Ss[wv][(mf * 16 + lr) * 72 + ks * 32 + lk * 8]);
#pragma unroll
        for (int nf = 0; nf < 4; ++nf)
          xfr[nf] = *reinterpret_cast<const bf16x8_t*>(Xtt + (nf * 16 + lr) * 72 + ks * 32 + lk * 8);
#pragma unroll
        for (int mf = 0; mf < 4; ++mf)
#pragma unroll
          for (int nf = 0; nf < 4; ++nf)
            acc[mf][nf] = __builtin_amdgcn_mfma_f32_16x16x32_bf16(afr[mf], xfr[nf], acc[mf][nf], 0, 0, 0);
      }
    }
  }

  float Dh = Dp[h];
#pragma unroll
  for (int mf = 0; mf < 4; ++mf)
#pragma unroll
    for (int nf = 0; nf < 4; ++nf) {
#pragma unroll
      for (int r = 0; r < 4; ++r) {
        int i = wv * 64 + mf * 16 + lk * 4 + r;
        size_t row = (size_t)(base + i);
        int p = ph * 64 + nf * 16 + lr;
        float xr = bf2f(xBC[row * 1152 + h * 128 + p]);
        yb[row * 1024 + h * 128 + p] = f2bf(acc[mf][nf][r] + Dh * xr);
      }
    }
}

// ---------------- RMSNorm over concat(y, z) bf16 -> bf16 ----------------
__global__ __launch_bounds__(256) void rmsnorm_kernel(const unsigned short* __restrict__ y,
                                                      const unsigned short* __restrict__ z,
                                                      const float* __restrict__ nw,
                                                      unsigned short* __restrict__ out) {
  int row = blockIdx.x, tid = threadIdx.x;
  ushort4 ya = reinterpret_cast<const ushort4*>(y + (size_t)row * 1024)[tid];
  ushort4 za = reinterpret_cast<const ushort4*>(z + (size_t)row * 1024)[tid];
  float yf[4] = {bf2f(ya.x), bf2f(ya.y), bf2f(ya.z), bf2f(ya.w)};
  float zf[4] = {bf2f(za.x), bf2f(za.y), bf2f(za.z), bf2f(za.w)};
  float ss = yf[0] * yf[0] + yf[1] * yf[1] + yf[2] * yf[2] + yf[3] * yf[3] +
             zf[0] * zf[0] + zf[1] * zf[1] + zf[2] * zf[2] + zf[3] * zf[3];
#pragma unroll
  for (int off = 32; off > 0; off >>= 1) ss += __shfl_down(ss, off, 64);
  __shared__ float red[4];
  __shared__ float stot;
  int lane = tid & 63, wv = tid >> 6;
  if (lane == 0) red[wv] = ss;
  __syncthreads();
  if (tid == 0) stot = rsqrtf((red[0] + red[1] + red[2] + red[3]) * (1.f / 2048.f) + 1e-5f);
  __syncthreads();
  float s = stot;
  float4 w1 = reinterpret_cast<const float4*>(nw)[tid];
  float4 w2 = reinterpret_cast<const float4*>(nw + 1024)[tid];
  ushort4 o1, o2;
  o1.x = f2bf(yf[0] * s * w1.x); o1.y = f2bf(yf[1] * s * w1.y);
  o1.z = f2bf(yf[2] * s * w1.z); o1.w = f2bf(yf[3] * s * w1.w);
  o2.x = f2bf(zf[0] * s * w2.x); o2.y = f2bf(zf[1] * s * w2.y);
  o2.z = f2bf(zf[2] * s * w2.z); o2.w = f2bf(zf[3] * s * w2.w);
  reinterpret_cast<ushort4*>(out + (size_t)row * 2048)[tid] = o1;
  reinterpret_cast<ushort4*>(out + (size_t)row * 2048 + 1024)[tid] = o2;
}

extern "C" void kernel_launch(void* const* d_in, const int* in_sizes, int n_in,
                              void* d_out, int out_size, void* d_ws, size_t ws_size,
                              hipStream_t stream) {
  const float* u       = (const float*)d_in[0];
  const float* W_in    = (const float*)d_in[1];
  const float* xconv_w = (const float*)d_in[2];
  const float* xconv_b = (const float*)d_in[3];
  const float* zconv_w = (const float*)d_in[4];
  const float* zconv_b = (const float*)d_in[5];
  const float* dt_bias = (const float*)d_in[6];
  const float* Alog    = (const float*)d_in[7];
  const float* Dp      = (const float*)d_in[8];
  const float* norm_w  = (const float*)d_in[9];
  const float* W_out   = (const float*)d_in[10];
  float* out = (float*)d_out;

  char* ws = (char*)d_ws;
  size_t o = 0;
  auto alc = [&](size_t bytes) { void* p = (void*)(ws + o); o = (o + bytes + 255) & ~(size_t)255; return p; };
  unsigned short* A1     = (unsigned short*)alc(16777216);  // u bf16 (8192x1024)
  unsigned short* Wt1    = (unsigned short*)alc(4456448);   // W_in^T cols 0..2175 (2176x1024)
  unsigned short* Wt2    = (unsigned short*)alc(4194304);   // W_out^T (1024x2048)
  unsigned short* zx     = (unsigned short*)alc(35651584);  // 8192x2176 bf16
  float*          dtv    = (float*)alc(262144);             // 8192x8
  float*          csb    = (float*)alc(262144);             // [b][h][c][256]
  unsigned short* xBC    = (unsigned short*)alc(18874368);  // 8192x1152 bf16
  unsigned short* zc     = (unsigned short*)alc(16777216);  // 8192x1024 bf16
  float*          stat   = (float*)alc(8388608);            // [bch][p][n] fp32
  float*          prevb  = (float*)alc(8388608);
  unsigned short* yb     = (unsigned short*)alc(16777216);  // 8192x1024 bf16
  unsigned short* normed = (unsigned short*)alc(33554432);  // 8192x2048 bf16
  (void)ws_size; (void)in_sizes; (void)n_in; (void)out_size;

  dim3 tb(32, 8);
  cvt_bf16_kernel<<<8192, 256, 0, stream>>>(u, A1, 2097152);
  transpose_bf16_kernel<<<dim3(68, 32), tb, 0, stream>>>(W_in, Wt1, 1024, 2176, 2184);
  transpose_bf16_kernel<<<dim3(32, 64), tb, 0, stream>>>(W_out, Wt2, 2048, 1024, 1024);
  gemm_bt_kernel<1><<<dim3(64, 17), 256, 0, stream>>>(A1, Wt1, (void*)zx, 1024, 2176);
  dt_kernel<<<8192, 256, 0, stream>>>(u, W_in, dt_bias, dtv);
  conv_silu_kernel<<<18432, 256, 0, stream>>>(zx + 1024, 2176, xconv_w, xconv_b, xBC, 1152);
  conv_silu_kernel<<<16384, 256, 0, stream>>>(zx, 2176, zconv_w, zconv_b, zc, 1024);
  cumsum_kernel<<<256, 256, 0, stream>>>(dtv, Alog, csb);
  states_mfma_kernel<<<512, 256, 0, stream>>>(xBC, dtv, csb, stat);
  scan_kernel<<<16, 256, 0, stream>>>(stat, csb, prevb);
  fused_y_kernel<<<512, 256, 0, stream>>>(xBC, dtv, csb, prevb, Dp, yb);
  rmsnorm_kernel<<<8192, 256, 0, stream>>>(yb, zc, norm_w, normed);
  gemm_bt_kernel<0><<<dim3(64, 8), 256, 0, stream>>>(normed, Wt2, (void*)out, 2048, 1024);
}

// Round 3
// 388.264 us; speedup vs baseline: 1.3653x; 1.1611x over previous
//
#include <hip/hip_runtime.h>
#include <stdint.h>

#define DEV __device__ __forceinline__

typedef __attribute__((ext_vector_type(8))) short bf16x8_t;   // 8 bf16 in 4 VGPRs
typedef __attribute__((ext_vector_type(4))) float f32x4_t;

DEV unsigned short f2bf(float f) {
  union { float f; uint32_t u; } x; x.f = f;
  uint32_t r = x.u + 0x7fffu + ((x.u >> 16) & 1u);
  return (unsigned short)(r >> 16);
}
DEV float bf2f(unsigned short u) {
  union { uint32_t u; float f; } x; x.u = ((uint32_t)u) << 16;
  return x.f;
}

#define GLOAD_LDS16(g, l)                                                              \
  __builtin_amdgcn_global_load_lds((const __attribute__((address_space(1))) unsigned int*)(g), \
                                   (__attribute__((address_space(3))) unsigned int*)(l), 16, 0, 0)

// ---------------- convert fp32 -> bf16 (vectorized) ----------------
__global__ __launch_bounds__(256) void cvt_bf16_kernel(const float* __restrict__ in,
                                                       unsigned short* __restrict__ out, int n4) {
  int i = blockIdx.x * 256 + threadIdx.x;
  if (i >= n4) return;
  float4 v = reinterpret_cast<const float4*>(in)[i];
  ushort4 o;
  o.x = f2bf(v.x); o.y = f2bf(v.y); o.z = f2bf(v.z); o.w = f2bf(v.w);
  reinterpret_cast<ushort4*>(out)[i] = o;
}

// ---------------- transpose fp32 (R x C, row stride) -> bf16 (C x R) ----------------
__global__ void transpose_bf16_kernel(const float* __restrict__ in, unsigned short* __restrict__ out,
                                      int R, int C, int stride) {
  __shared__ float t[32][33];
  int bx = blockIdx.x, by = blockIdx.y;
  int tx = threadIdx.x, ty = threadIdx.y;
#pragma unroll
  for (int q = 0; q < 4; ++q) {
    int r = by * 32 + ty + q * 8, c = bx * 32 + tx;
    t[ty + q * 8][tx] = in[(size_t)r * stride + c];
  }
  __syncthreads();
#pragma unroll
  for (int q = 0; q < 4; ++q) {
    int oc = bx * 32 + ty + q * 8;
    int orr = by * 32 + tx;
    out[(size_t)oc * R + orr] = f2bf(t[tx][ty + q * 8]);
  }
}

// ---------------- bf16 MFMA GEMM with global_load_lds staging ----------------
template <int OBF>
__global__ __launch_bounds__(256) void gemm_bt_kernel(const unsigned short* __restrict__ A,
                                                      const unsigned short* __restrict__ Bt,
                                                      void* __restrict__ Cout, int K, int ldc) {
  __shared__ __align__(16) unsigned short As[128 * 32];
  __shared__ __align__(16) unsigned short Bs[128 * 32];
  int tid = threadIdx.x;
  int lane = tid & 63, wave = tid >> 6;
  int wm = wave >> 1, wn = wave & 1;
  int lr = lane & 15, lk = lane >> 4;
  long tileM = (long)blockIdx.x * 128, tileN = (long)blockIdx.y * 128;
  f32x4_t acc[4][4];
#pragma unroll
  for (int i = 0; i < 4; ++i)
#pragma unroll
    for (int j = 0; j < 4; ++j) acc[i][j] = f32x4_t{0.f, 0.f, 0.f, 0.f};

  for (int k0 = 0; k0 < K; k0 += 32) {
    __syncthreads();
#pragma unroll
    for (int it = 0; it < 2; ++it) {
      int chunk = (it * 4 + wave) * 64 + lane;   // 0..511, 16B each
      int row = chunk >> 2;
      int kb = (chunk & 3) * 8;
      unsigned int ldsoff = (unsigned int)((it * 4 + wave) * 1024);
      GLOAD_LDS16(A + (size_t)(tileM + row) * K + k0 + kb, (char*)As + ldsoff);
      GLOAD_LDS16(Bt + (size_t)(tileN + row) * K + k0 + kb, (char*)Bs + ldsoff);
    }
    __syncthreads();
    bf16x8_t af[4], bfv[4];
#pragma unroll
    for (int mf = 0; mf < 4; ++mf) {
      int row = wm * 64 + mf * 16 + lr;
      af[mf] = *reinterpret_cast<const bf16x8_t*>((const char*)As + row * 64 + lk * 16);
    }
#pragma unroll
    for (int nf = 0; nf < 4; ++nf) {
      int row = wn * 64 + nf * 16 + lr;
      bfv[nf] = *reinterpret_cast<const bf16x8_t*>((const char*)Bs + row * 64 + lk * 16);
    }
#pragma unroll
    for (int mf = 0; mf < 4; ++mf)
#pragma unroll
      for (int nf = 0; nf < 4; ++nf)
        acc[mf][nf] = __builtin_amdgcn_mfma_f32_16x16x32_bf16(af[mf], bfv[nf], acc[mf][nf], 0, 0, 0);
  }
#pragma unroll
  for (int mf = 0; mf < 4; ++mf)
#pragma unroll
    for (int nf = 0; nf < 4; ++nf) {
      long r0 = tileM + wm * 64 + mf * 16 + lk * 4;
      long c0 = tileN + wn * 64 + nf * 16 + lr;
#pragma unroll
      for (int r = 0; r < 4; ++r) {
        if (OBF)
          ((unsigned short*)Cout)[(size_t)(r0 + r) * ldc + c0] = f2bf(acc[mf][nf][r]);
        else
          ((float*)Cout)[(size_t)(r0 + r) * ldc + c0] = acc[mf][nf][r];
      }
    }
}

// ---------------- dt = softplus(u @ W_in[:,2176:2184] + dt_bias), exact fp32 ----------------
__global__ __launch_bounds__(256) void dt_kernel(const float* __restrict__ u, const float* __restrict__ W_in,
                                                 const float* __restrict__ dt_bias, float* __restrict__ dtv) {
  int row = blockIdx.x, tid = threadIdx.x;
  float ps[8] = {0.f, 0.f, 0.f, 0.f, 0.f, 0.f, 0.f, 0.f};
  const float* ur = u + (size_t)row * 1024;
#pragma unroll
  for (int kk = 0; kk < 4; ++kk) {
    int k = tid + kk * 256;
    float uv = ur[k];
    const float* wr = W_in + (size_t)k * 2184 + 2176;
#pragma unroll
    for (int h = 0; h < 8; ++h) ps[h] += uv * wr[h];
  }
#pragma unroll
  for (int h = 0; h < 8; ++h)
#pragma unroll
    for (int off = 32; off > 0; off >>= 1) ps[h] += __shfl_down(ps[h], off, 64);
  __shared__ float red[4][8];
  int lane = tid & 63, wv = tid >> 6;
  if (lane == 0) {
#pragma unroll
    for (int h = 0; h < 8; ++h) red[wv][h] = ps[h];
  }
  __syncthreads();
  if (tid < 8) {
    float s = red[0][tid] + red[1][tid] + red[2][tid] + red[3][tid] + dt_bias[tid];
    float sp = (s > 20.f) ? s : log1pf(expf(s));
    dtv[(size_t)row * 8 + tid] = sp;
  }
}

// ---------------- causal depthwise conv (width 4) + SiLU, bf16 in/out ----------------
__global__ __launch_bounds__(256) void conv_silu_kernel(const unsigned short* __restrict__ in, int in_stride,
                                                        const float* __restrict__ w, const float* __restrict__ bias,
                                                        unsigned short* __restrict__ outp, int C) {
  int C2 = C >> 1;
  int idx = blockIdx.x * 256 + threadIdx.x;
  if (idx >= 8192 * C2) return;
  int c2 = idx % C2;
  int row = idx / C2;
  int c = c2 * 2;
  int t = row & 4095, bb = row >> 12;
  float a0 = bias[c], a1 = bias[c + 1];
#pragma unroll
  for (int k = 0; k < 4; ++k) {
    int tt = t - 3 + k;
    if (tt >= 0) {
      unsigned int v = *reinterpret_cast<const unsigned int*>(in + (size_t)((bb << 12) + tt) * in_stride + c);
      a0 += bf2f((unsigned short)(v & 0xffffu)) * w[c * 4 + k];
      a1 += bf2f((unsigned short)(v >> 16)) * w[(c + 1) * 4 + k];
    }
  }
  a0 = a0 / (1.f + expf(-a0));
  a1 = a1 / (1.f + expf(-a1));
  unsigned int o = (unsigned int)f2bf(a0) | ((unsigned int)f2bf(a1) << 16);
  *reinterpret_cast<unsigned int*>(outp + (size_t)row * C + c) = o;
}

// ---------------- SSD pass 1 (chunk=64): cumsum + S + Y_diag + chunk states ----------------
// grid: (b*64+c)*8+h  (1024 blocks), 256 threads (4 waves), wave wv owns i-band [wv*16, wv*16+16)
__global__ __launch_bounds__(256) void ssd1_kernel(const unsigned short* __restrict__ xBC,
                                                   const float* __restrict__ dtv,
                                                   const float* __restrict__ Alog,
                                                   float* __restrict__ csb,
                                                   float* __restrict__ stat,
                                                   float* __restrict__ ypart) {
  int blk = blockIdx.x;
  int h = blk & 7, bc = blk >> 3;
  int c = bc & 63, b = bc >> 6;
  int tid = threadIdx.x, lane = tid & 63, wv = tid >> 6;
  int lr = lane & 15, lk = lane >> 4;
  int base = b * 4096 + c * 64;

  __shared__ float csc[64], dts[64], ew[64];
  __shared__ __align__(16) unsigned short Xd[128 * 72];   // [p][j^swz] = x[j][p]*dt_j
  __shared__ __align__(16) unsigned short Bnj[64 * 72];   // [n][j^swz] = B[j][n]
  __shared__ __align__(16) unsigned short Ss[64 * 72];    // [i][j] masked decayed S

  if (wv == 0) {
    int j = lane;
    float dt = dtv[(size_t)(base + j) * 8 + h];
    float A = -expf(Alog[h]);
    float s = dt * A;
#pragma unroll
    for (int off = 1; off < 64; off <<= 1) {
      float v = __shfl_up(s, off, 64);
      if (lane >= off) s += v;
    }
    float csl = __shfl(s, 63, 64);
    csc[j] = s; dts[j] = dt; ew[j] = expf(csl - s);
    csb[(size_t)blk * 64 + j] = s;
  }
  __syncthreads();

  // stage Xd (64 rows j x 128 p, transposed, dt-scaled, j-swizzled by (p>>3)&7)
#pragma unroll
  for (int rr = 0; rr < 4; ++rr) {
    int j = rr * 16 + (tid >> 4);
    int pc = tid & 15;
    bf16x8_t v = *reinterpret_cast<const bf16x8_t*>(xBC + (size_t)(base + j) * 1152 + h * 128 + pc * 8);
    float dj = dts[j];
    int js = j ^ ((pc & 7) << 3);     // p>>3 == pc for all 8 elems
#pragma unroll
    for (int e = 0; e < 8; ++e) {
      int p = pc * 8 + e;
      Xd[p * 72 + js] = f2bf(bf2f((unsigned short)v[e]) * dj);
    }
  }
  // stage Bnj (64 rows j x 64 n, transposed, j-swizzled by (n>>3)&7)
#pragma unroll
  for (int rr = 0; rr < 2; ++rr) {
    int j = rr * 32 + (tid >> 3);
    int nc = tid & 7;
    bf16x8_t v = *reinterpret_cast<const bf16x8_t*>(xBC + (size_t)(base + j) * 1152 + 1024 + nc * 8);
    int js = j ^ ((nc & 7) << 3);
#pragma unroll
    for (int e = 0; e < 8; ++e) {
      int n = nc * 8 + e;
      Bnj[n * 72 + js] = (unsigned short)v[e];
    }
  }

  // S = C @ B^T with direct-global fragments (rows i in wave band)
  bf16x8_t cf[2];
  {
    size_t crow = (size_t)(base + wv * 16 + lr) * 1152 + 1088;
    cf[0] = *reinterpret_cast<const bf16x8_t*>(xBC + crow + lk * 8);
    cf[1] = *reinterpret_cast<const bf16x8_t*>(xBC + crow + 32 + lk * 8);
  }
  f32x4_t sacc[4];
#pragma unroll
  for (int jf = 0; jf < 4; ++jf) sacc[jf] = f32x4_t{0.f, 0.f, 0.f, 0.f};
#pragma unroll
  for (int ks = 0; ks < 2; ++ks) {
#pragma unroll
    for (int jf = 0; jf < 4; ++jf) {
      bf16x8_t bv = *reinterpret_cast<const bf16x8_t*>(
          xBC + (size_t)(base + jf * 16 + lr) * 1152 + 1024 + ks * 32 + lk * 8);
      sacc[jf] = __builtin_amdgcn_mfma_f32_16x16x32_bf16(cf[ks], bv, sacc[jf], 0, 0, 0);
    }
  }
  __syncthreads();   // Xd/Bnj staged; also guards Ss writes below vs reads after

  // mask + decay -> bf16 Ss[i][j]
  {
    float csi[4];
#pragma unroll
    for (int r = 0; r < 4; ++r) csi[r] = csc[wv * 16 + lk * 4 + r];
#pragma unroll
    for (int jf = 0; jf < 4; ++jf) {
      int j = jf * 16 + lr;
      float csj = csc[j];
#pragma unroll
      for (int r = 0; r < 4; ++r) {
        int i = wv * 16 + lk * 4 + r;
        float w = (j <= i) ? expf(csi[r] - csj) : 0.f;
        Ss[i * 72 + j] = f2bf(sacc[jf][r] * w);
      }
    }
  }
  __syncthreads();

  // Y_diag = Ss @ Xd^T  (output 16 x 128 per wave)
  f32x4_t yacc[8];
#pragma unroll
  for (int pf = 0; pf < 8; ++pf) yacc[pf] = f32x4_t{0.f, 0.f, 0.f, 0.f};
  bf16x8_t sa[2];
  sa[0] = *reinterpret_cast<const bf16x8_t*>(Ss + (wv * 16 + lr) * 72 + lk * 8);
  sa[1] = *reinterpret_cast<const bf16x8_t*>(Ss + (wv * 16 + lr) * 72 + 32 + lk * 8);
#pragma unroll
  for (int ks = 0; ks < 2; ++ks) {
    int jb = ks * 32 + lk * 8;
#pragma unroll
    for (int pf = 0; pf < 8; ++pf) {
      int p = pf * 16 + lr;
      bf16x8_t xv = *reinterpret_cast<const bf16x8_t*>(Xd + p * 72 + (jb ^ (((p >> 3) & 7) << 3)));
      yacc[pf] = __builtin_amdgcn_mfma_f32_16x16x32_bf16(sa[ks], xv, yacc[pf], 0, 0, 0);
    }
  }

  // states = (Xd * ew)^T-weighted @ B  (output 32 x 64 per wave: p-band wv*32..+32)
  f32x4_t st[2][4];
#pragma unroll
  for (int pb = 0; pb < 2; ++pb)
#pragma unroll
    for (int nf = 0; nf < 4; ++nf) st[pb][nf] = f32x4_t{0.f, 0.f, 0.f, 0.f};
#pragma unroll
  for (int pb = 0; pb < 2; ++pb) {
    int p = wv * 32 + pb * 16 + lr;
#pragma unroll
    for (int ks = 0; ks < 2; ++ks) {
      int jb = ks * 32 + lk * 8;
      bf16x8_t xv = *reinterpret_cast<const bf16x8_t*>(Xd + p * 72 + (jb ^ (((p >> 3) & 7) << 3)));
      bf16x8_t xs;
#pragma unroll
      for (int e = 0; e < 8; ++e) xs[e] = (short)f2bf(bf2f((unsigned short)xv[e]) * ew[jb + e]);
#pragma unroll
      for (int nf = 0; nf < 4; ++nf) {
        int n = nf * 16 + lr;
        bf16x8_t bv = *reinterpret_cast<const bf16x8_t*>(Bnj + n * 72 + (jb ^ (((n >> 3) & 7) << 3)));
        st[pb][nf] = __builtin_amdgcn_mfma_f32_16x16x32_bf16(xs, bv, st[pb][nf], 0, 0, 0);
      }
    }
  }

  // write ypart (fp32) and stat (fp32)
#pragma unroll
  for (int pf = 0; pf < 8; ++pf)
#pragma unroll
    for (int r = 0; r < 4; ++r) {
      int i = wv * 16 + lk * 4 + r;
      ypart[(size_t)(base + i) * 1024 + h * 128 + pf * 16 + lr] = yacc[pf][r];
    }
  float* so = stat + (size_t)blk * 8192;
#pragma unroll
  for (int pb = 0; pb < 2; ++pb)
#pragma unroll
    for (int nf = 0; nf < 4; ++nf)
#pragma unroll
      for (int r = 0; r < 4; ++r)
        so[(size_t)(wv * 32 + pb * 16 + lk * 4 + r) * 64 + nf * 16 + lr] = st[pb][nf][r];
}

// ---------------- element-parallel inter-chunk scan (64 chunks), prev -> bf16 ----------------
__global__ __launch_bounds__(256) void scan_kernel(const float* __restrict__ stat,
                                                   const float* __restrict__ csb,
                                                   unsigned short* __restrict__ prevb) {
  int bh = blockIdx.x >> 5;          // b*8+h
  int part = blockIdx.x & 31;
  int h = bh & 7, b = bh >> 3;
  int e = part * 256 + threadIdx.x;
  float carry = 0.f;
  for (int c = 0; c < 64; ++c) {
    size_t blk = (size_t)(b * 64 + c) * 8 + h;
    size_t idx = blk * 8192 + e;
    prevb[idx] = f2bf(carry);
    float dec = expf(csb[blk * 64 + 63]);
    carry = stat[idx] + dec * carry;
  }
}

// ---------------- SSD pass 2: Y = ypart + (C e^cs) @ prev^T + D x ----------------
__global__ __launch_bounds__(256) void ssd2_kernel(const unsigned short* __restrict__ xBC,
                                                   const float* __restrict__ csb,
                                                   const unsigned short* __restrict__ prevb,
                                                   const float* __restrict__ Dp,
                                                   const float* __restrict__ ypart,
                                                   unsigned short* __restrict__ yb) {
  int blk = blockIdx.x;
  int h = blk & 7, bc = blk >> 3;
  int c = bc & 63, b = bc >> 6;
  int tid = threadIdx.x, lane = tid & 63, wv = tid >> 6;
  int lr = lane & 15, lk = lane >> 4;
  int base = b * 4096 + c * 64;
  __shared__ float csc[64];
  if (tid < 64) csc[tid] = csb[(size_t)blk * 64 + tid];
  __syncthreads();

  float sc = expf(csc[wv * 16 + lr]);
  bf16x8_t ca[2];
  {
    size_t crow = (size_t)(base + wv * 16 + lr) * 1152 + 1088;
#pragma unroll
    for (int ks = 0; ks < 2; ++ks) {
      bf16x8_t v = *reinterpret_cast<const bf16x8_t*>(xBC + crow + ks * 32 + lk * 8);
      bf16x8_t d;
#pragma unroll
      for (int e = 0; e < 8; ++e) d[e] = (short)f2bf(bf2f((unsigned short)v[e]) * sc);
      ca[ks] = d;
    }
  }
  f32x4_t acc[8];
#pragma unroll
  for (int pf = 0; pf < 8; ++pf) acc[pf] = f32x4_t{0.f, 0.f, 0.f, 0.f};
#pragma unroll
  for (int ks = 0; ks < 2; ++ks) {
#pragma unroll
    for (int pf = 0; pf < 8; ++pf) {
      bf16x8_t pv = *reinterpret_cast<const bf16x8_t*>(
          prevb + (size_t)blk * 8192 + (size_t)(pf * 16 + lr) * 64 + ks * 32 + lk * 8);
      acc[pf] = __builtin_amdgcn_mfma_f32_16x16x32_bf16(ca[ks], pv, acc[pf], 0, 0, 0);
    }
  }
  float Dh = Dp[h];
#pragma unroll
  for (int pf = 0; pf < 8; ++pf)
#pragma unroll
    for (int r = 0; r < 4; ++r) {
      int i = wv * 16 + lk * 4 + r;
      size_t row = (size_t)(base + i);
      int p = pf * 16 + lr;
      float xr = bf2f(xBC[row * 1152 + h * 128 + p]);
      float yv = ypart[row * 1024 + h * 128 + p] + acc[pf][r] + Dh * xr;
      yb[row * 1024 + h * 128 + p] = f2bf(yv);
    }
}

// ---------------- RMSNorm over concat(y, z) bf16 -> bf16 ----------------
__global__ __launch_bounds__(256) void rmsnorm_kernel(const unsigned short* __restrict__ y,
                                                      const unsigned short* __restrict__ z,
                                                      const float* __restrict__ nw,
                                                      unsigned short* __restrict__ out) {
  int row = blockIdx.x, tid = threadIdx.x;
  ushort4 ya = reinterpret_cast<const ushort4*>(y + (size_t)row * 1024)[tid];
  ushort4 za = reinterpret_cast<const ushort4*>(z + (size_t)row * 1024)[tid];
  float yf[4] = {bf2f(ya.x), bf2f(ya.y), bf2f(ya.z), bf2f(ya.w)};
  float zf[4] = {bf2f(za.x), bf2f(za.y), bf2f(za.z), bf2f(za.w)};
  float ss = yf[0] * yf[0] + yf[1] * yf[1] + yf[2] * yf[2] + yf[3] * yf[3] +
             zf[0] * zf[0] + zf[1] * zf[1] + zf[2] * zf[2] + zf[3] * zf[3];
#pragma unroll
  for (int off = 32; off > 0; off >>= 1) ss += __shfl_down(ss, off, 64);
  __shared__ float red[4];
  __shared__ float stot;
  int lane = tid & 63, wv = tid >> 6;
  if (lane == 0) red[wv] = ss;
  __syncthreads();
  if (tid == 0) stot = rsqrtf((red[0] + red[1] + red[2] + red[3]) * (1.f / 2048.f) + 1e-5f);
  __syncthreads();
  float s = stot;
  float4 w1 = reinterpret_cast<const float4*>(nw)[tid];
  float4 w2 = reinterpret_cast<const float4*>(nw + 1024)[tid];
  ushort4 o1, o2;
  o1.x = f2bf(yf[0] * s * w1.x); o1.y = f2bf(yf[1] * s * w1.y);
  o1.z = f2bf(yf[2] * s * w1.z); o1.w = f2bf(yf[3] * s * w1.w);
  o2.x = f2bf(zf[0] * s * w2.x); o2.y = f2bf(zf[1] * s * w2.y);
  o2.z = f2bf(zf[2] * s * w2.z); o2.w = f2bf(zf[3] * s * w2.w);
  reinterpret_cast<ushort4*>(out + (size_t)row * 2048)[tid] = o1;
  reinterpret_cast<ushort4*>(out + (size_t)row * 2048 + 1024)[tid] = o2;
}

extern "C" void kernel_launch(void* const* d_in, const int* in_sizes, int n_in,
                              void* d_out, int out_size, void* d_ws, size_t ws_size,
                              hipStream_t stream) {
  const float* u       = (const float*)d_in[0];
  const float* W_in    = (const float*)d_in[1];
  const float* xconv_w = (const float*)d_in[2];
  const float* xconv_b = (const float*)d_in[3];
  const float* zconv_w = (const float*)d_in[4];
  const float* zconv_b = (const float*)d_in[5];
  const float* dt_bias = (const float*)d_in[6];
  const float* Alog    = (const float*)d_in[7];
  const float* Dp      = (const float*)d_in[8];
  const float* norm_w  = (const float*)d_in[9];
  const float* W_out   = (const float*)d_in[10];
  float* out = (float*)d_out;

  char* ws = (char*)d_ws;
  size_t o = 0;
  auto alc = [&](size_t bytes) { void* p = (void*)(ws + o); o = (o + bytes + 255) & ~(size_t)255; return p; };
  // region reuse (lifetimes disjoint, each region fully rewritten every call):
  char* regA = (char*)alc(16777216);    // A1 (u bf16) -> yb (bf16)
  unsigned short* Wt1    = (unsigned short*)alc(4456448);   // W_in^T cols 0..2175
  unsigned short* Wt2    = (unsigned short*)alc(4194304);   // W_out^T
  char* regZ = (char*)alc(35651584);    // zx (bf16 8192x2176) -> ypart (fp32 8192x1024)
  float*          dtv    = (float*)alc(262144);             // 8192x8
  float*          csb    = (float*)alc(262144);             // [b][c64][h][64]
  unsigned short* xBC    = (unsigned short*)alc(18874368);  // 8192x1152 bf16
  unsigned short* zc     = (unsigned short*)alc(16777216);  // 8192x1024 bf16
  char* regS = (char*)alc(33554432);    // stat (fp32 [bch][p][n]) -> normed (bf16 8192x2048)
  unsigned short* prevb  = (unsigned short*)alc(16777216);  // [bch][p][n] bf16
  (void)ws_size; (void)in_sizes; (void)n_in; (void)out_size;

  unsigned short* A1     = (unsigned short*)regA;
  unsigned short* yb     = (unsigned short*)regA;
  unsigned short* zx     = (unsigned short*)regZ;
  float*          ypart  = (float*)regZ;
  float*          stat   = (float*)regS;
  unsigned short* normed = (unsigned short*)regS;

  dim3 tb(32, 8);
  cvt_bf16_kernel<<<8192, 256, 0, stream>>>(u, A1, 2097152);
  transpose_bf16_kernel<<<dim3(68, 32), tb, 0, stream>>>(W_in, Wt1, 1024, 2176, 2184);
  transpose_bf16_kernel<<<dim3(32, 64), tb, 0, stream>>>(W_out, Wt2, 2048, 1024, 1024);
  gemm_bt_kernel<1><<<dim3(64, 17), 256, 0, stream>>>(A1, Wt1, (void*)zx, 1024, 2176);
  dt_kernel<<<8192, 256, 0, stream>>>(u, W_in, dt_bias, dtv);
  conv_silu_kernel<<<18432, 256, 0, stream>>>(zx + 1024, 2176, xconv_w, xconv_b, xBC, 1152);
  conv_silu_kernel<<<16384, 256, 0, stream>>>(zx, 2176, zconv_w, zconv_b, zc, 1024);
  ssd1_kernel<<<1024, 256, 0, stream>>>(xBC, dtv, Alog, csb, stat, ypart);
  scan_kernel<<<512, 256, 0, stream>>>(stat, csb, prevb);
  ssd2_kernel<<<1024, 256, 0, stream>>>(xBC, csb, prevb, Dp, ypart, yb);
  rmsnorm_kernel<<<8192, 256, 0, stream>>>(yb, zc, norm_w, normed);
  gemm_bt_kernel<0><<<dim3(64, 8), 256, 0, stream>>>(normed, Wt2, (void*)out, 2048, 1024);
}

// Round 4
// 298.352 us; speedup vs baseline: 1.7767x; 1.3014x over previous
//
#include <hip/hip_runtime.h>
#include <stdint.h>

#define DEV __device__ __forceinline__

typedef __attribute__((ext_vector_type(8))) short bf16x8_t;   // 8 bf16 in 4 VGPRs
typedef __attribute__((ext_vector_type(4))) float f32x4_t;

DEV unsigned short f2bf(float f) {
  union { float f; uint32_t u; } x; x.f = f;
  uint32_t r = x.u + 0x7fffu + ((x.u >> 16) & 1u);
  return (unsigned short)(r >> 16);
}
DEV float bf2f(unsigned short u) {
  union { uint32_t u; float f; } x; x.u = ((uint32_t)u) << 16;
  return x.f;
}

#define GLOAD_LDS16(g, l)                                                              \
  __builtin_amdgcn_global_load_lds((const __attribute__((address_space(1))) unsigned int*)(g), \
                                   (__attribute__((address_space(3))) unsigned int*)(l), 16, 0, 0)

// ---------------- convert fp32 -> bf16 (vectorized) ----------------
__global__ __launch_bounds__(256) void cvt_bf16_kernel(const float* __restrict__ in,
                                                       unsigned short* __restrict__ out, int n4) {
  int i = blockIdx.x * 256 + threadIdx.x;
  if (i >= n4) return;
  float4 v = reinterpret_cast<const float4*>(in)[i];
  ushort4 o;
  o.x = f2bf(v.x); o.y = f2bf(v.y); o.z = f2bf(v.z); o.w = f2bf(v.w);
  reinterpret_cast<ushort4*>(out)[i] = o;
}

// ---------------- transpose fp32 (R x C, row stride) -> bf16 (C x R) ----------------
__global__ void transpose_bf16_kernel(const float* __restrict__ in, unsigned short* __restrict__ out,
                                      int R, int C, int stride) {
  __shared__ float t[32][33];
  int bx = blockIdx.x, by = blockIdx.y;
  int tx = threadIdx.x, ty = threadIdx.y;
#pragma unroll
  for (int q = 0; q < 4; ++q) {
    int r = by * 32 + ty + q * 8, c = bx * 32 + tx;
    t[ty + q * 8][tx] = in[(size_t)r * stride + c];
  }
  __syncthreads();
#pragma unroll
  for (int q = 0; q < 4; ++q) {
    int oc = bx * 32 + ty + q * 8;
    int orr = by * 32 + tx;
    out[(size_t)oc * R + orr] = f2bf(t[tx][ty + q * 8]);
  }
}

// ---------------- bf16 MFMA GEMM with global_load_lds staging + XCD swizzle ----------------
template <int OBF>
__global__ __launch_bounds__(256) void gemm_bt_kernel(const unsigned short* __restrict__ A,
                                                      const unsigned short* __restrict__ Bt,
                                                      void* __restrict__ Cout, int K, int ldc) {
  __shared__ __align__(16) unsigned short As[128 * 32];
  __shared__ __align__(16) unsigned short Bs[128 * 32];
  int tid = threadIdx.x;
  int lane = tid & 63, wave = tid >> 6;
  int wm = wave >> 1, wn = wave & 1;
  int lr = lane & 15, lk = lane >> 4;
  // XCD-aware bijective swizzle (grid sizes here are divisible by 8)
  int gx = gridDim.x, gy = gridDim.y;
  int lin = blockIdx.y * gx + blockIdx.x;
  int nwg = gx * gy;
  int bx, by;
  if ((nwg & 7) == 0) {
    int cpx = nwg >> 3;
    int swz = (lin & 7) * cpx + (lin >> 3);
    bx = swz % gx; by = swz / gx;
  } else { bx = blockIdx.x; by = blockIdx.y; }
  long tileM = (long)bx * 128, tileN = (long)by * 128;
  f32x4_t acc[4][4];
#pragma unroll
  for (int i = 0; i < 4; ++i)
#pragma unroll
    for (int j = 0; j < 4; ++j) acc[i][j] = f32x4_t{0.f, 0.f, 0.f, 0.f};

  for (int k0 = 0; k0 < K; k0 += 32) {
    __syncthreads();
#pragma unroll
    for (int it = 0; it < 2; ++it) {
      int chunk = (it * 4 + wave) * 64 + lane;   // 0..511, 16B each
      int row = chunk >> 2;
      int kb = (chunk & 3) * 8;
      unsigned int ldsoff = (unsigned int)((it * 4 + wave) * 1024);
      GLOAD_LDS16(A + (size_t)(tileM + row) * K + k0 + kb, (char*)As + ldsoff);
      GLOAD_LDS16(Bt + (size_t)(tileN + row) * K + k0 + kb, (char*)Bs + ldsoff);
    }
    __syncthreads();
    bf16x8_t af[4], bfv[4];
#pragma unroll
    for (int mf = 0; mf < 4; ++mf) {
      int row = wm * 64 + mf * 16 + lr;
      af[mf] = *reinterpret_cast<const bf16x8_t*>((const char*)As + row * 64 + lk * 16);
    }
#pragma unroll
    for (int nf = 0; nf < 4; ++nf) {
      int row = wn * 64 + nf * 16 + lr;
      bfv[nf] = *reinterpret_cast<const bf16x8_t*>((const char*)Bs + row * 64 + lk * 16);
    }
#pragma unroll
    for (int mf = 0; mf < 4; ++mf)
#pragma unroll
      for (int nf = 0; nf < 4; ++nf)
        acc[mf][nf] = __builtin_amdgcn_mfma_f32_16x16x32_bf16(af[mf], bfv[nf], acc[mf][nf], 0, 0, 0);
  }
#pragma unroll
  for (int mf = 0; mf < 4; ++mf)
#pragma unroll
    for (int nf = 0; nf < 4; ++nf) {
      long r0 = tileM + wm * 64 + mf * 16 + lk * 4;
      long c0 = tileN + wn * 64 + nf * 16 + lr;
#pragma unroll
      for (int r = 0; r < 4; ++r) {
        if (OBF)
          ((unsigned short*)Cout)[(size_t)(r0 + r) * ldc + c0] = f2bf(acc[mf][nf][r]);
        else
          ((float*)Cout)[(size_t)(r0 + r) * ldc + c0] = acc[mf][nf][r];
      }
    }
}

// ---------------- dt = softplus(u @ W_in[:,2176:2184] + dt_bias), exact fp32 ----------------
__global__ __launch_bounds__(256) void dt_kernel(const float* __restrict__ u, const float* __restrict__ W_in,
                                                 const float* __restrict__ dt_bias, float* __restrict__ dtv) {
  int row = blockIdx.x, tid = threadIdx.x;
  float ps[8] = {0.f, 0.f, 0.f, 0.f, 0.f, 0.f, 0.f, 0.f};
  const float* ur = u + (size_t)row * 1024;
#pragma unroll
  for (int kk = 0; kk < 4; ++kk) {
    int k = tid + kk * 256;
    float uv = ur[k];
    const float* wr = W_in + (size_t)k * 2184 + 2176;
#pragma unroll
    for (int h = 0; h < 8; ++h) ps[h] += uv * wr[h];
  }
#pragma unroll
  for (int h = 0; h < 8; ++h)
#pragma unroll
    for (int off = 32; off > 0; off >>= 1) ps[h] += __shfl_down(ps[h], off, 64);
  __shared__ float red[4][8];
  int lane = tid & 63, wv = tid >> 6;
  if (lane == 0) {
#pragma unroll
    for (int h = 0; h < 8; ++h) red[wv][h] = ps[h];
  }
  __syncthreads();
  if (tid < 8) {
    float s = red[0][tid] + red[1][tid] + red[2][tid] + red[3][tid] + dt_bias[tid];
    float sp = (s > 20.f) ? s : log1pf(expf(s));
    dtv[(size_t)row * 8 + tid] = sp;
  }
}

// ---------------- causal dwconv(4)+SiLU, register-tiled: 8 t x 8 ch per thread ----------------
template <int C, int IN_STRIDE>
__global__ __launch_bounds__(256) void conv_silu_tile_kernel(const unsigned short* __restrict__ in,
                                                             const float* __restrict__ w,
                                                             const float* __restrict__ bias,
                                                             unsigned short* __restrict__ outp) {
  constexpr int CG = C / 8;
  int idx = blockIdx.x * 256 + threadIdx.x;
  int ch_grp = idx % CG;
  int tb = idx / CG;                 // 0..1023  (b*512 + tblock)
  int t0 = (tb & 511) * 8;
  int b = tb >> 9;
  int ch0 = ch_grp * 8;

  float4 wv[8];
#pragma unroll
  for (int e = 0; e < 8; ++e) wv[e] = *reinterpret_cast<const float4*>(w + (ch0 + e) * 4);
  float bs[8];
  {
    float4 b0 = *reinterpret_cast<const float4*>(bias + ch0);
    float4 b1 = *reinterpret_cast<const float4*>(bias + ch0 + 4);
    bs[0] = b0.x; bs[1] = b0.y; bs[2] = b0.z; bs[3] = b0.w;
    bs[4] = b1.x; bs[5] = b1.y; bs[6] = b1.z; bs[7] = b1.w;
  }

  float rows[11][8];
#pragma unroll
  for (int k = 0; k < 11; ++k) {
    int t = t0 - 3 + k;
    if (t >= 0) {
      bf16x8_t v = *reinterpret_cast<const bf16x8_t*>(in + (size_t)((b << 12) + t) * IN_STRIDE + ch0);
#pragma unroll
      for (int e = 0; e < 8; ++e) rows[k][e] = bf2f((unsigned short)v[e]);
    } else {
#pragma unroll
      for (int e = 0; e < 8; ++e) rows[k][e] = 0.f;
    }
  }

#pragma unroll
  for (int tp = 0; tp < 8; ++tp) {
    bf16x8_t o;
#pragma unroll
    for (int e = 0; e < 8; ++e) {
      float a = bs[e] + wv[e].x * rows[tp][e] + wv[e].y * rows[tp + 1][e] +
                wv[e].z * rows[tp + 2][e] + wv[e].w * rows[tp + 3][e];
      a = a / (1.f + expf(-a));
      o[e] = (short)f2bf(a);
    }
    *reinterpret_cast<bf16x8_t*>(outp + (size_t)((b << 12) + t0 + tp) * C + ch0) = o;
  }
}

// ---------------- SSD pass 1 (chunk=64): cumsum + S + Y_diag + chunk states ----------------
// grid: (b*64+c)*8+h  (1024 blocks), 256 threads (4 waves), wave wv owns i-band [wv*16, wv*16+16)
__global__ __launch_bounds__(256) void ssd1_kernel(const unsigned short* __restrict__ xBC,
                                                   const float* __restrict__ dtv,
                                                   const float* __restrict__ Alog,
                                                   float* __restrict__ csb,
                                                   unsigned short* __restrict__ stat,
                                                   float* __restrict__ ypart) {
  int blk = blockIdx.x;
  int h = blk & 7, bc = blk >> 3;
  int c = bc & 63, b = bc >> 6;
  int tid = threadIdx.x, lane = tid & 63, wv = tid >> 6;
  int lr = lane & 15, lk = lane >> 4;
  int base = b * 4096 + c * 64;

  __shared__ float csc[64], dts[64], ew[64];
  __shared__ __align__(16) unsigned short Xd[128 * 72];   // [p][j^swz] = x[j][p]*dt_j
  __shared__ __align__(16) unsigned short Bnj[64 * 72];   // [n][j^swz] = B[j][n]
  __shared__ __align__(16) unsigned short Ss[64 * 72];    // [i][j] masked decayed S

  if (wv == 0) {
    int j = lane;
    float dt = dtv[(size_t)(base + j) * 8 + h];
    float A = -expf(Alog[h]);
    float s = dt * A;
#pragma unroll
    for (int off = 1; off < 64; off <<= 1) {
      float v = __shfl_up(s, off, 64);
      if (lane >= off) s += v;
    }
    float csl = __shfl(s, 63, 64);
    csc[j] = s; dts[j] = dt; ew[j] = expf(csl - s);
    csb[(size_t)blk * 64 + j] = s;
  }
  __syncthreads();

  // stage Xd (64 rows j x 128 p, transposed, dt-scaled, j-swizzled by (p>>3)&7)
#pragma unroll
  for (int rr = 0; rr < 4; ++rr) {
    int j = rr * 16 + (tid >> 4);
    int pc = tid & 15;
    bf16x8_t v = *reinterpret_cast<const bf16x8_t*>(xBC + (size_t)(base + j) * 1152 + h * 128 + pc * 8);
    float dj = dts[j];
    int js = j ^ ((pc & 7) << 3);
#pragma unroll
    for (int e = 0; e < 8; ++e) {
      int p = pc * 8 + e;
      Xd[p * 72 + js] = f2bf(bf2f((unsigned short)v[e]) * dj);
    }
  }
  // stage Bnj (64 rows j x 64 n, transposed, j-swizzled by (n>>3)&7)
#pragma unroll
  for (int rr = 0; rr < 2; ++rr) {
    int j = rr * 32 + (tid >> 3);
    int nc = tid & 7;
    bf16x8_t v = *reinterpret_cast<const bf16x8_t*>(xBC + (size_t)(base + j) * 1152 + 1024 + nc * 8);
    int js = j ^ ((nc & 7) << 3);
#pragma unroll
    for (int e = 0; e < 8; ++e) {
      int n = nc * 8 + e;
      Bnj[n * 72 + js] = (unsigned short)v[e];
    }
  }

  // S = C @ B^T with direct-global fragments (rows i in wave band)
  bf16x8_t cf[2];
  {
    size_t crow = (size_t)(base + wv * 16 + lr) * 1152 + 1088;
    cf[0] = *reinterpret_cast<const bf16x8_t*>(xBC + crow + lk * 8);
    cf[1] = *reinterpret_cast<const bf16x8_t*>(xBC + crow + 32 + lk * 8);
  }
  f32x4_t sacc[4];
#pragma unroll
  for (int jf = 0; jf < 4; ++jf) sacc[jf] = f32x4_t{0.f, 0.f, 0.f, 0.f};
#pragma unroll
  for (int ks = 0; ks < 2; ++ks) {
#pragma unroll
    for (int jf = 0; jf < 4; ++jf) {
      bf16x8_t bv = *reinterpret_cast<const bf16x8_t*>(
          xBC + (size_t)(base + jf * 16 + lr) * 1152 + 1024 + ks * 32 + lk * 8);
      sacc[jf] = __builtin_amdgcn_mfma_f32_16x16x32_bf16(cf[ks], bv, sacc[jf], 0, 0, 0);
    }
  }
  __syncthreads();

  // mask + decay -> bf16 Ss[i][j]
  {
    float csi[4];
#pragma unroll
    for (int r = 0; r < 4; ++r) csi[r] = csc[wv * 16 + lk * 4 + r];
#pragma unroll
    for (int jf = 0; jf < 4; ++jf) {
      int j = jf * 16 + lr;
      float csj = csc[j];
#pragma unroll
      for (int r = 0; r < 4; ++r) {
        int i = wv * 16 + lk * 4 + r;
        float w = (j <= i) ? expf(csi[r] - csj) : 0.f;
        Ss[i * 72 + j] = f2bf(sacc[jf][r] * w);
      }
    }
  }
  __syncthreads();

  // Y_diag = Ss @ Xd^T  (output 16 x 128 per wave)
  f32x4_t yacc[8];
#pragma unroll
  for (int pf = 0; pf < 8; ++pf) yacc[pf] = f32x4_t{0.f, 0.f, 0.f, 0.f};
  bf16x8_t sa[2];
  sa[0] = *reinterpret_cast<const bf16x8_t*>(Ss + (wv * 16 + lr) * 72 + lk * 8);
  sa[1] = *reinterpret_cast<const bf16x8_t*>(Ss + (wv * 16 + lr) * 72 + 32 + lk * 8);
#pragma unroll
  for (int ks = 0; ks < 2; ++ks) {
    int jb = ks * 32 + lk * 8;
#pragma unroll
    for (int pf = 0; pf < 8; ++pf) {
      int p = pf * 16 + lr;
      bf16x8_t xv = *reinterpret_cast<const bf16x8_t*>(Xd + p * 72 + (jb ^ (((p >> 3) & 7) << 3)));
      yacc[pf] = __builtin_amdgcn_mfma_f32_16x16x32_bf16(sa[ks], xv, yacc[pf], 0, 0, 0);
    }
  }

  // states = (Xd * ew)^T-weighted @ B
  f32x4_t st[2][4];
#pragma unroll
  for (int pb = 0; pb < 2; ++pb)
#pragma unroll
    for (int nf = 0; nf < 4; ++nf) st[pb][nf] = f32x4_t{0.f, 0.f, 0.f, 0.f};
#pragma unroll
  for (int pb = 0; pb < 2; ++pb) {
    int p = wv * 32 + pb * 16 + lr;
#pragma unroll
    for (int ks = 0; ks < 2; ++ks) {
      int jb = ks * 32 + lk * 8;
      bf16x8_t xv = *reinterpret_cast<const bf16x8_t*>(Xd + p * 72 + (jb ^ (((p >> 3) & 7) << 3)));
      bf16x8_t xs;
#pragma unroll
      for (int e = 0; e < 8; ++e) xs[e] = (short)f2bf(bf2f((unsigned short)xv[e]) * ew[jb + e]);
#pragma unroll
      for (int nf = 0; nf < 4; ++nf) {
        int n = nf * 16 + lr;
        bf16x8_t bv = *reinterpret_cast<const bf16x8_t*>(Bnj + n * 72 + (jb ^ (((n >> 3) & 7) << 3)));
        st[pb][nf] = __builtin_amdgcn_mfma_f32_16x16x32_bf16(xs, bv, st[pb][nf], 0, 0, 0);
      }
    }
  }

#pragma unroll
  for (int pf = 0; pf < 8; ++pf)
#pragma unroll
    for (int r = 0; r < 4; ++r) {
      int i = wv * 16 + lk * 4 + r;
      ypart[(size_t)(base + i) * 1024 + h * 128 + pf * 16 + lr] = yacc[pf][r];
    }
  unsigned short* so = stat + (size_t)blk * 8192;
#pragma unroll
  for (int pb = 0; pb < 2; ++pb)
#pragma unroll
    for (int nf = 0; nf < 4; ++nf)
#pragma unroll
      for (int r = 0; r < 4; ++r)
        so[(size_t)(wv * 32 + pb * 16 + lk * 4 + r) * 64 + nf * 16 + lr] = f2bf(st[pb][nf][r]);
}

// ---------------- element-parallel inter-chunk scan (64 chunks), prev -> bf16 ----------------
__global__ __launch_bounds__(256) void scan_kernel(const unsigned short* __restrict__ stat,
                                                   const float* __restrict__ csb,
                                                   unsigned short* __restrict__ prevb) {
  int bh = blockIdx.x >> 5;          // b*8+h
  int part = blockIdx.x & 31;
  int h = bh & 7, b = bh >> 3;
  int e = part * 256 + threadIdx.x;
  float carry = 0.f;
  for (int c = 0; c < 64; ++c) {
    size_t blk = (size_t)(b * 64 + c) * 8 + h;
    size_t idx = blk * 8192 + e;
    prevb[idx] = f2bf(carry);
    float dec = expf(csb[blk * 64 + 63]);
    carry = bf2f(stat[idx]) + dec * carry;
  }
}

// ---------------- SSD pass 2: Y = ypart + (C e^cs) @ prev^T + D x ----------------
__global__ __launch_bounds__(256) void ssd2_kernel(const unsigned short* __restrict__ xBC,
                                                   const float* __restrict__ csb,
                                                   const unsigned short* __restrict__ prevb,
                                                   const float* __restrict__ Dp,
                                                   const float* __restrict__ ypart,
                                                   unsigned short* __restrict__ yb) {
  int blk = blockIdx.x;
  int h = blk & 7, bc = blk >> 3;
  int c = bc & 63, b = bc >> 6;
  int tid = threadIdx.x, lane = tid & 63, wv = tid >> 6;
  int lr = lane & 15, lk = lane >> 4;
  int base = b * 4096 + c * 64;
  __shared__ float csc[64];
  if (tid < 64) csc[tid] = csb[(size_t)blk * 64 + tid];
  __syncthreads();

  float sc = expf(csc[wv * 16 + lr]);
  bf16x8_t ca[2];
  {
    size_t crow = (size_t)(base + wv * 16 + lr) * 1152 + 1088;
#pragma unroll
    for (int ks = 0; ks < 2; ++ks) {
      bf16x8_t v = *reinterpret_cast<const bf16x8_t*>(xBC + crow + ks * 32 + lk * 8);
      bf16x8_t d;
#pragma unroll
      for (int e = 0; e < 8; ++e) d[e] = (short)f2bf(bf2f((unsigned short)v[e]) * sc);
      ca[ks] = d;
    }
  }
  f32x4_t acc[8];
#pragma unroll
  for (int pf = 0; pf < 8; ++pf) acc[pf] = f32x4_t{0.f, 0.f, 0.f, 0.f};
#pragma unroll
  for (int ks = 0; ks < 2; ++ks) {
#pragma unroll
    for (int pf = 0; pf < 8; ++pf) {
      bf16x8_t pv = *reinterpret_cast<const bf16x8_t*>(
          prevb + (size_t)blk * 8192 + (size_t)(pf * 16 + lr) * 64 + ks * 32 + lk * 8);
      acc[pf] = __builtin_amdgcn_mfma_f32_16x16x32_bf16(ca[ks], pv, acc[pf], 0, 0, 0);
    }
  }
  float Dh = Dp[h];
#pragma unroll
  for (int pf = 0; pf < 8; ++pf)
#pragma unroll
    for (int r = 0; r < 4; ++r) {
      int i = wv * 16 + lk * 4 + r;
      size_t row = (size_t)(base + i);
      int p = pf * 16 + lr;
      float xr = bf2f(xBC[row * 1152 + h * 128 + p]);
      float yv = ypart[row * 1024 + h * 128 + p] + acc[pf][r] + Dh * xr;
      yb[row * 1024 + h * 128 + p] = f2bf(yv);
    }
}

// ---------------- RMSNorm over concat(y, z) bf16 -> bf16 ----------------
__global__ __launch_bounds__(256) void rmsnorm_kernel(const unsigned short* __restrict__ y,
                                                      const unsigned short* __restrict__ z,
                                                      const float* __restrict__ nw,
                                                      unsigned short* __restrict__ out) {
  int row = blockIdx.x, tid = threadIdx.x;
  ushort4 ya = reinterpret_cast<const ushort4*>(y + (size_t)row * 1024)[tid];
  ushort4 za = reinterpret_cast<const ushort4*>(z + (size_t)row * 1024)[tid];
  float yf[4] = {bf2f(ya.x), bf2f(ya.y), bf2f(ya.z), bf2f(ya.w)};
  float zf[4] = {bf2f(za.x), bf2f(za.y), bf2f(za.z), bf2f(za.w)};
  float ss = yf[0] * yf[0] + yf[1] * yf[1] + yf[2] * yf[2] + yf[3] * yf[3] +
             zf[0] * zf[0] + zf[1] * zf[1] + zf[2] * zf[2] + zf[3] * zf[3];
#pragma unroll
  for (int off = 32; off > 0; off >>= 1) ss += __shfl_down(ss, off, 64);
  __shared__ float red[4];
  __shared__ float stot;
  int lane = tid & 63, wv = tid >> 6;
  if (lane == 0) red[wv] = ss;
  __syncthreads();
  if (tid == 0) stot = rsqrtf((red[0] + red[1] + red[2] + red[3]) * (1.f / 2048.f) + 1e-5f);
  __syncthreads();
  float s = stot;
  float4 w1 = reinterpret_cast<const float4*>(nw)[tid];
  float4 w2 = reinterpret_cast<const float4*>(nw + 1024)[tid];
  ushort4 o1, o2;
  o1.x = f2bf(yf[0] * s * w1.x); o1.y = f2bf(yf[1] * s * w1.y);
  o1.z = f2bf(yf[2] * s * w1.z); o1.w = f2bf(yf[3] * s * w1.w);
  o2.x = f2bf(zf[0] * s * w2.x); o2.y = f2bf(zf[1] * s * w2.y);
  o2.z = f2bf(zf[2] * s * w2.z); o2.w = f2bf(zf[3] * s * w2.w);
  reinterpret_cast<ushort4*>(out + (size_t)row * 2048)[tid] = o1;
  reinterpret_cast<ushort4*>(out + (size_t)row * 2048 + 1024)[tid] = o2;
}

extern "C" void kernel_launch(void* const* d_in, const int* in_sizes, int n_in,
                              void* d_out, int out_size, void* d_ws, size_t ws_size,
                              hipStream_t stream) {
  const float* u       = (const float*)d_in[0];
  const float* W_in    = (const float*)d_in[1];
  const float* xconv_w = (const float*)d_in[2];
  const float* xconv_b = (const float*)d_in[3];
  const float* zconv_w = (const float*)d_in[4];
  const float* zconv_b = (const float*)d_in[5];
  const float* dt_bias = (const float*)d_in[6];
  const float* Alog    = (const float*)d_in[7];
  const float* Dp      = (const float*)d_in[8];
  const float* norm_w  = (const float*)d_in[9];
  const float* W_out   = (const float*)d_in[10];
  float* out = (float*)d_out;

  char* ws = (char*)d_ws;
  size_t o = 0;
  auto alc = [&](size_t bytes) { void* p = (void*)(ws + o); o = (o + bytes + 255) & ~(size_t)255; return p; };
  char* regA = (char*)alc(16777216);    // A1 (u bf16) -> yb (bf16)
  unsigned short* Wt1    = (unsigned short*)alc(4456448);   // W_in^T cols 0..2175
  unsigned short* Wt2    = (unsigned short*)alc(4194304);   // W_out^T
  char* regZ = (char*)alc(35651584);    // zx (bf16 8192x2176) -> ypart (fp32 8192x1024)
  float*          dtv    = (float*)alc(262144);             // 8192x8
  float*          csb    = (float*)alc(262144);             // [b][c64][h][64]
  unsigned short* xBC    = (unsigned short*)alc(18874368);  // 8192x1152 bf16
  unsigned short* zc     = (unsigned short*)alc(16777216);  // 8192x1024 bf16
  char* regS = (char*)alc(33554432);    // stat (bf16 [bch][p][n]) -> normed (bf16 8192x2048)
  unsigned short* prevb  = (unsigned short*)alc(16777216);  // [bch][p][n] bf16
  (void)ws_size; (void)in_sizes; (void)n_in; (void)out_size;

  unsigned short* A1     = (unsigned short*)regA;
  unsigned short* yb     = (unsigned short*)regA;
  unsigned short* zx     = (unsigned short*)regZ;
  float*          ypart  = (float*)regZ;
  unsigned short* stat   = (unsigned short*)regS;
  unsigned short* normed = (unsigned short*)regS;

  dim3 tb(32, 8);
  cvt_bf16_kernel<<<8192, 256, 0, stream>>>(u, A1, 2097152);
  transpose_bf16_kernel<<<dim3(68, 32), tb, 0, stream>>>(W_in, Wt1, 1024, 2176, 2184);
  transpose_bf16_kernel<<<dim3(32, 64), tb, 0, stream>>>(W_out, Wt2, 2048, 1024, 1024);
  gemm_bt_kernel<1><<<dim3(64, 17), 256, 0, stream>>>(A1, Wt1, (void*)zx, 1024, 2176);
  dt_kernel<<<8192, 256, 0, stream>>>(u, W_in, dt_bias, dtv);
  conv_silu_tile_kernel<1152, 2176><<<576, 256, 0, stream>>>(zx + 1024, xconv_w, xconv_b, xBC);
  conv_silu_tile_kernel<1024, 2176><<<512, 256, 0, stream>>>(zx, zconv_w, zconv_b, zc);
  ssd1_kernel<<<1024, 256, 0, stream>>>(xBC, dtv, Alog, csb, stat, ypart);
  scan_kernel<<<512, 256, 0, stream>>>(stat, csb, prevb);
  ssd2_kernel<<<1024, 256, 0, stream>>>(xBC, csb, prevb, Dp, ypart, yb);
  rmsnorm_kernel<<<8192, 256, 0, stream>>>(yb, zc, norm_w, normed);
  gemm_bt_kernel<0><<<dim3(64, 8), 256, 0, stream>>>(normed, Wt2, (void*)out, 2048, 1024);
}

// Round 5
// 297.729 us; speedup vs baseline: 1.7805x; 1.0021x over previous
//
#include <hip/hip_runtime.h>
#include <stdint.h>

#define DEV __device__ __forceinline__

typedef __attribute__((ext_vector_type(8))) short bf16x8_t;   // 8 bf16 in 4 VGPRs
typedef __attribute__((ext_vector_type(4))) float f32x4_t;

DEV unsigned short f2bf(float f) {
  union { float f; uint32_t u; } x; x.f = f;
  uint32_t r = x.u + 0x7fffu + ((x.u >> 16) & 1u);
  return (unsigned short)(r >> 16);
}
DEV float bf2f(unsigned short u) {
  union { uint32_t u; float f; } x; x.u = ((uint32_t)u) << 16;
  return x.f;
}

#define GLOAD_LDS16(g, l)                                                              \
  __builtin_amdgcn_global_load_lds((const __attribute__((address_space(1))) unsigned int*)(g), \
                                   (__attribute__((address_space(3))) unsigned int*)(l), 16, 0, 0)

// ---------------- convert fp32 -> bf16 (vectorized) ----------------
__global__ __launch_bounds__(256) void cvt_bf16_kernel(const float* __restrict__ in,
                                                       unsigned short* __restrict__ out, int n4) {
  int i = blockIdx.x * 256 + threadIdx.x;
  if (i >= n4) return;
  float4 v = reinterpret_cast<const float4*>(in)[i];
  ushort4 o;
  o.x = f2bf(v.x); o.y = f2bf(v.y); o.z = f2bf(v.z); o.w = f2bf(v.w);
  reinterpret_cast<ushort4*>(out)[i] = o;
}

// ---------------- transpose fp32 (R x C_in, row stride) -> bf16 (C_out x R), zero-pad c >= C_in ----------------
__global__ void transpose_bf16_kernel(const float* __restrict__ in, unsigned short* __restrict__ out,
                                      int R, int Cin, int stride) {
  __shared__ float t[32][33];
  int bx = blockIdx.x, by = blockIdx.y;
  int tx = threadIdx.x, ty = threadIdx.y;
#pragma unroll
  for (int q = 0; q < 4; ++q) {
    int r = by * 32 + ty + q * 8, c = bx * 32 + tx;
    t[ty + q * 8][tx] = (c < Cin) ? in[(size_t)r * stride + c] : 0.f;
  }
  __syncthreads();
#pragma unroll
  for (int q = 0; q < 4; ++q) {
    int oc = bx * 32 + ty + q * 8;
    int orr = by * 32 + tx;
    out[(size_t)oc * R + orr] = f2bf(t[tx][ty + q * 8]);
  }
}

// ================= 256-wide MFMA GEMM, 8 waves, dbuf LDS, counted vmcnt =================
// C(M x 256-col tiles) = A(MxK bf16) * Bt(NxK bf16)^T
// BM=256: waves 2x4, per-wave 128x64, LDS 128KB. BM=128: waves 1x8, per-wave 128x32, LDS 96KB.
// Fragment-major LDS: block(16 rows x 32 k) = 1024B, lane l holds row (l&15), k (l>>4)*8.
template <int BM, int OBF>
__global__ __launch_bounds__(512, 2) void gemm256_kernel(const unsigned short* __restrict__ A,
                                                         const unsigned short* __restrict__ Bt,
                                                         void* __restrict__ Cout, int K, int ldc, int gx) {
  constexpr int NF = (BM == 256) ? 4 : 2;      // B fragments per wave per phase
  constexpr int ABLK = BM / 16;                // A blocks per ks region
  constexpr int AISS = BM / 128;               // A stage issues per thread per ks
  constexpr int AKS = ABLK * 1024;             // A bytes per ks region
  constexpr int ABYTES = 2 * AKS;
  constexpr int BUFSZ = ABYTES + 32768;        // + B (256x64x2B)
  __shared__ __align__(16) char lds[2 * BUFSZ];

  int tid = threadIdx.x, lane = tid & 63, wv = tid >> 6;
  int lr = lane & 15, lk = lane >> 4;

  // XCD-aware bijective swizzle on 1-D grid (grid % 8 == 0 here)
  int nwg = gridDim.x;
  int lin = blockIdx.x;
  int wg = lin;
  if ((nwg & 7) == 0) { int cpx = nwg >> 3; wg = (lin & 7) * cpx + (lin >> 3); }
  long tileM = (long)(wg % gx) * BM;
  long tileN = (long)(wg / gx) * 256;

  int wm = (BM == 256) ? (wv >> 2) : 0;
  int wn = (BM == 256) ? (wv & 3) : wv;
  int aoffblk = wm * 8;
  int ncolb = wn * NF;

  // staging source pointers (per-lane, fragment-major pre-permutation)
  const unsigned short* gA[AISS];
#pragma unroll
  for (int i = 0; i < AISS; ++i)
    gA[i] = A + (size_t)(tileM + (i * 8 + wv) * 16 + lr) * K + lk * 8;
  const unsigned short* gB[2];
#pragma unroll
  for (int i = 0; i < 2; ++i)
    gB[i] = Bt + (size_t)(tileN + (i * 8 + wv) * 16 + lr) * K + lk * 8;

#define STAGE256(bufv, ksv, k0v)                                                           \
  do {                                                                                     \
    _Pragma("unroll") for (int i_ = 0; i_ < AISS; ++i_)                                    \
        GLOAD_LDS16(gA[i_] + (k0v) + (ksv) * 32,                                           \
                    lds + (bufv) * BUFSZ + (ksv) * AKS + ((i_ * 8 + wv) << 10));           \
    _Pragma("unroll") for (int i_ = 0; i_ < 2; ++i_)                                       \
        GLOAD_LDS16(gB[i_] + (k0v) + (ksv) * 32,                                           \
                    lds + (bufv) * BUFSZ + ABYTES + (ksv) * 16384 + ((i_ * 8 + wv) << 10));\
  } while (0)

  f32x4_t acc[8][NF];
#pragma unroll
  for (int mf = 0; mf < 8; ++mf)
#pragma unroll
    for (int nf = 0; nf < NF; ++nf) acc[mf][nf] = f32x4_t{0.f, 0.f, 0.f, 0.f};

  int NT = K >> 6;
  // prologue: stage tile 0 (both k-slices) into buf 0
  STAGE256(0, 0, 0);
  STAGE256(0, 1, 0);

  for (int t = 0; t < NT; ++t) {
    int buf = t & 1;
    int k0n = (t + 1) << 6;
    const char* base = lds + buf * BUFSZ;
#pragma unroll
    for (int ks = 0; ks < 2; ++ks) {
      // counted wait: the loads this phase needs are 2 issue-batches old;
      // exactly one batch (L loads) was issued after them (except final phase: 0).
      if (t == NT - 1 && ks == 1) {
        asm volatile("s_waitcnt vmcnt(0)" ::: "memory");
      } else if constexpr (BM == 256) {
        asm volatile("s_waitcnt vmcnt(4)" ::: "memory");
      } else {
        asm volatile("s_waitcnt vmcnt(3)" ::: "memory");
      }
      __builtin_amdgcn_s_barrier();
      __builtin_amdgcn_sched_barrier(0);
      if (t + 1 < NT) {
        if (ks == 0) STAGE256(buf ^ 1, 0, k0n);
        else         STAGE256(buf ^ 1, 1, k0n);
      }
      bf16x8_t a[8], b[NF];
#pragma unroll
      for (int mf = 0; mf < 8; ++mf)
        a[mf] = *reinterpret_cast<const bf16x8_t*>(base + ks * AKS + (aoffblk + mf) * 1024 + lane * 16);
#pragma unroll
      for (int nf = 0; nf < NF; ++nf)
        b[nf] = *reinterpret_cast<const bf16x8_t*>(base + ABYTES + ks * 16384 + (ncolb + nf) * 1024 + lane * 16);
      __builtin_amdgcn_s_setprio(1);
#pragma unroll
      for (int mf = 0; mf < 8; ++mf)
#pragma unroll
        for (int nf = 0; nf < NF; ++nf)
          acc[mf][nf] = __builtin_amdgcn_mfma_f32_16x16x32_bf16(a[mf], b[nf], acc[mf][nf], 0, 0, 0);
      __builtin_amdgcn_s_setprio(0);
    }
  }
#undef STAGE256

#pragma unroll
  for (int mf = 0; mf < 8; ++mf)
#pragma unroll
    for (int nf = 0; nf < NF; ++nf) {
      long r0 = tileM + (aoffblk + mf) * 16 + lk * 4;
      long c0 = tileN + (ncolb + nf) * 16 + lr;
#pragma unroll
      for (int r = 0; r < 4; ++r) {
        if (OBF)
          ((unsigned short*)Cout)[(size_t)(r0 + r) * ldc + c0] = f2bf(acc[mf][nf][r]);
        else
          ((float*)Cout)[(size_t)(r0 + r) * ldc + c0] = acc[mf][nf][r];
      }
    }
}

// ---------------- dt = softplus(u @ W_in[:,2176:2184] + dt_bias), exact fp32 ----------------
__global__ __launch_bounds__(256) void dt_kernel(const float* __restrict__ u, const float* __restrict__ W_in,
                                                 const float* __restrict__ dt_bias, float* __restrict__ dtv) {
  int row = blockIdx.x, tid = threadIdx.x;
  float ps[8] = {0.f, 0.f, 0.f, 0.f, 0.f, 0.f, 0.f, 0.f};
  const float* ur = u + (size_t)row * 1024;
#pragma unroll
  for (int kk = 0; kk < 4; ++kk) {
    int k = tid + kk * 256;
    float uv = ur[k];
    const float* wr = W_in + (size_t)k * 2184 + 2176;
#pragma unroll
    for (int h = 0; h < 8; ++h) ps[h] += uv * wr[h];
  }
#pragma unroll
  for (int h = 0; h < 8; ++h)
#pragma unroll
    for (int off = 32; off > 0; off >>= 1) ps[h] += __shfl_down(ps[h], off, 64);
  __shared__ float red[4][8];
  int lane = tid & 63, wv = tid >> 6;
  if (lane == 0) {
#pragma unroll
    for (int h = 0; h < 8; ++h) red[wv][h] = ps[h];
  }
  __syncthreads();
  if (tid < 8) {
    float s = red[0][tid] + red[1][tid] + red[2][tid] + red[3][tid] + dt_bias[tid];
    float sp = (s > 20.f) ? s : log1pf(expf(s));
    dtv[(size_t)row * 8 + tid] = sp;
  }
}

// ---------------- causal dwconv(4)+SiLU, register-tiled: 8 t x 8 ch per thread ----------------
template <int C, int IN_STRIDE>
__global__ __launch_bounds__(256) void conv_silu_tile_kernel(const unsigned short* __restrict__ in,
                                                             const float* __restrict__ w,
                                                             const float* __restrict__ bias,
                                                             unsigned short* __restrict__ outp) {
  constexpr int CG = C / 8;
  int idx = blockIdx.x * 256 + threadIdx.x;
  int ch_grp = idx % CG;
  int tb = idx / CG;                 // b*512 + tblock
  int t0 = (tb & 511) * 8;
  int b = tb >> 9;
  int ch0 = ch_grp * 8;

  float4 wv[8];
#pragma unroll
  for (int e = 0; e < 8; ++e) wv[e] = *reinterpret_cast<const float4*>(w + (ch0 + e) * 4);
  float bs[8];
  {
    float4 b0 = *reinterpret_cast<const float4*>(bias + ch0);
    float4 b1 = *reinterpret_cast<const float4*>(bias + ch0 + 4);
    bs[0] = b0.x; bs[1] = b0.y; bs[2] = b0.z; bs[3] = b0.w;
    bs[4] = b1.x; bs[5] = b1.y; bs[6] = b1.z; bs[7] = b1.w;
  }

  float rows[11][8];
#pragma unroll
  for (int k = 0; k < 11; ++k) {
    int t = t0 - 3 + k;
    if (t >= 0) {
      bf16x8_t v = *reinterpret_cast<const bf16x8_t*>(in + (size_t)((b << 12) + t) * IN_STRIDE + ch0);
#pragma unroll
      for (int e = 0; e < 8; ++e) rows[k][e] = bf2f((unsigned short)v[e]);
    } else {
#pragma unroll
      for (int e = 0; e < 8; ++e) rows[k][e] = 0.f;
    }
  }

#pragma unroll
  for (int tp = 0; tp < 8; ++tp) {
    bf16x8_t o;
#pragma unroll
    for (int e = 0; e < 8; ++e) {
      float a = bs[e] + wv[e].x * rows[tp][e] + wv[e].y * rows[tp + 1][e] +
                wv[e].z * rows[tp + 2][e] + wv[e].w * rows[tp + 3][e];
      a = a / (1.f + expf(-a));
      o[e] = (short)f2bf(a);
    }
    *reinterpret_cast<bf16x8_t*>(outp + (size_t)((b << 12) + t0 + tp) * C + ch0) = o;
  }
}

// ---------------- SSD pass 1 (chunk=64): cumsum + S + Y_diag + chunk states ----------------
__global__ __launch_bounds__(256) void ssd1_kernel(const unsigned short* __restrict__ xBC,
                                                   const float* __restrict__ dtv,
                                                   const float* __restrict__ Alog,
                                                   float* __restrict__ csb,
                                                   unsigned short* __restrict__ stat,
                                                   float* __restrict__ ypart) {
  int blk = blockIdx.x;
  int h = blk & 7, bc = blk >> 3;
  int c = bc & 63, b = bc >> 6;
  int tid = threadIdx.x, lane = tid & 63, wv = tid >> 6;
  int lr = lane & 15, lk = lane >> 4;
  int base = b * 4096 + c * 64;

  __shared__ float csc[64], dts[64], ew[64];
  __shared__ __align__(16) unsigned short Xd[128 * 72];
  __shared__ __align__(16) unsigned short Bnj[64 * 72];
  __shared__ __align__(16) unsigned short Ss[64 * 72];

  if (wv == 0) {
    int j = lane;
    float dt = dtv[(size_t)(base + j) * 8 + h];
    float A = -expf(Alog[h]);
    float s = dt * A;
#pragma unroll
    for (int off = 1; off < 64; off <<= 1) {
      float v = __shfl_up(s, off, 64);
      if (lane >= off) s += v;
    }
    float csl = __shfl(s, 63, 64);
    csc[j] = s; dts[j] = dt; ew[j] = expf(csl - s);
    csb[(size_t)blk * 64 + j] = s;
  }
  __syncthreads();

#pragma unroll
  for (int rr = 0; rr < 4; ++rr) {
    int j = rr * 16 + (tid >> 4);
    int pc = tid & 15;
    bf16x8_t v = *reinterpret_cast<const bf16x8_t*>(xBC + (size_t)(base + j) * 1152 + h * 128 + pc * 8);
    float dj = dts[j];
    int js = j ^ ((pc & 7) << 3);
#pragma unroll
    for (int e = 0; e < 8; ++e) {
      int p = pc * 8 + e;
      Xd[p * 72 + js] = f2bf(bf2f((unsigned short)v[e]) * dj);
    }
  }
#pragma unroll
  for (int rr = 0; rr < 2; ++rr) {
    int j = rr * 32 + (tid >> 3);
    int nc = tid & 7;
    bf16x8_t v = *reinterpret_cast<const bf16x8_t*>(xBC + (size_t)(base + j) * 1152 + 1024 + nc * 8);
    int js = j ^ ((nc & 7) << 3);
#pragma unroll
    for (int e = 0; e < 8; ++e) {
      int n = nc * 8 + e;
      Bnj[n * 72 + js] = (unsigned short)v[e];
    }
  }

  bf16x8_t cf[2];
  {
    size_t crow = (size_t)(base + wv * 16 + lr) * 1152 + 1088;
    cf[0] = *reinterpret_cast<const bf16x8_t*>(xBC + crow + lk * 8);
    cf[1] = *reinterpret_cast<const bf16x8_t*>(xBC + crow + 32 + lk * 8);
  }
  f32x4_t sacc[4];
#pragma unroll
  for (int jf = 0; jf < 4; ++jf) sacc[jf] = f32x4_t{0.f, 0.f, 0.f, 0.f};
#pragma unroll
  for (int ks = 0; ks < 2; ++ks) {
#pragma unroll
    for (int jf = 0; jf < 4; ++jf) {
      bf16x8_t bv = *reinterpret_cast<const bf16x8_t*>(
          xBC + (size_t)(base + jf * 16 + lr) * 1152 + 1024 + ks * 32 + lk * 8);
      sacc[jf] = __builtin_amdgcn_mfma_f32_16x16x32_bf16(cf[ks], bv, sacc[jf], 0, 0, 0);
    }
  }
  __syncthreads();

  {
    float csi[4];
#pragma unroll
    for (int r = 0; r < 4; ++r) csi[r] = csc[wv * 16 + lk * 4 + r];
#pragma unroll
    for (int jf = 0; jf < 4; ++jf) {
      int j = jf * 16 + lr;
      float csj = csc[j];
#pragma unroll
      for (int r = 0; r < 4; ++r) {
        int i = wv * 16 + lk * 4 + r;
        float w = (j <= i) ? expf(csi[r] - csj) : 0.f;
        Ss[i * 72 + j] = f2bf(sacc[jf][r] * w);
      }
    }
  }
  __syncthreads();

  f32x4_t yacc[8];
#pragma unroll
  for (int pf = 0; pf < 8; ++pf) yacc[pf] = f32x4_t{0.f, 0.f, 0.f, 0.f};
  bf16x8_t sa[2];
  sa[0] = *reinterpret_cast<const bf16x8_t*>(Ss + (wv * 16 + lr) * 72 + lk * 8);
  sa[1] = *reinterpret_cast<const bf16x8_t*>(Ss + (wv * 16 + lr) * 72 + 32 + lk * 8);
#pragma unroll
  for (int ks = 0; ks < 2; ++ks) {
    int jb = ks * 32 + lk * 8;
#pragma unroll
    for (int pf = 0; pf < 8; ++pf) {
      int p = pf * 16 + lr;
      bf16x8_t xv = *reinterpret_cast<const bf16x8_t*>(Xd + p * 72 + (jb ^ (((p >> 3) & 7) << 3)));
      yacc[pf] = __builtin_amdgcn_mfma_f32_16x16x32_bf16(sa[ks], xv, yacc[pf], 0, 0, 0);
    }
  }

  f32x4_t st[2][4];
#pragma unroll
  for (int pb = 0; pb < 2; ++pb)
#pragma unroll
    for (int nf = 0; nf < 4; ++nf) st[pb][nf] = f32x4_t{0.f, 0.f, 0.f, 0.f};
#pragma unroll
  for (int pb = 0; pb < 2; ++pb) {
    int p = wv * 32 + pb * 16 + lr;
#pragma unroll
    for (int ks = 0; ks < 2; ++ks) {
      int jb = ks * 32 + lk * 8;
      bf16x8_t xv = *reinterpret_cast<const bf16x8_t*>(Xd + p * 72 + (jb ^ (((p >> 3) & 7) << 3)));
      bf16x8_t xs;
#pragma unroll
      for (int e = 0; e < 8; ++e) xs[e] = (short)f2bf(bf2f((unsigned short)xv[e]) * ew[jb + e]);
#pragma unroll
      for (int nf = 0; nf < 4; ++nf) {
        int n = nf * 16 + lr;
        bf16x8_t bv = *reinterpret_cast<const bf16x8_t*>(Bnj + n * 72 + (jb ^ (((n >> 3) & 7) << 3)));
        st[pb][nf] = __builtin_amdgcn_mfma_f32_16x16x32_bf16(xs, bv, st[pb][nf], 0, 0, 0);
      }
    }
  }

#pragma unroll
  for (int pf = 0; pf < 8; ++pf)
#pragma unroll
    for (int r = 0; r < 4; ++r) {
      int i = wv * 16 + lk * 4 + r;
      ypart[(size_t)(base + i) * 1024 + h * 128 + pf * 16 + lr] = yacc[pf][r];
    }
  unsigned short* so = stat + (size_t)blk * 8192;
#pragma unroll
  for (int pb = 0; pb < 2; ++pb)
#pragma unroll
    for (int nf = 0; nf < 4; ++nf)
#pragma unroll
      for (int r = 0; r < 4; ++r)
        so[(size_t)(wv * 32 + pb * 16 + lk * 4 + r) * 64 + nf * 16 + lr] = f2bf(st[pb][nf][r]);
}

// ---------------- element-parallel inter-chunk scan (64 chunks), prev -> bf16 ----------------
__global__ __launch_bounds__(256) void scan_kernel(const unsigned short* __restrict__ stat,
                                                   const float* __restrict__ csb,
                                                   unsigned short* __restrict__ prevb) {
  int bh = blockIdx.x >> 5;
  int part = blockIdx.x & 31;
  int h = bh & 7, b = bh >> 3;
  int e = part * 256 + threadIdx.x;
  float carry = 0.f;
  for (int c = 0; c < 64; ++c) {
    size_t blk = (size_t)(b * 64 + c) * 8 + h;
    size_t idx = blk * 8192 + e;
    prevb[idx] = f2bf(carry);
    float dec = expf(csb[blk * 64 + 63]);
    carry = bf2f(stat[idx]) + dec * carry;
  }
}

// ---------------- SSD pass 2: Y = ypart + (C e^cs) @ prev^T + D x ----------------
__global__ __launch_bounds__(256) void ssd2_kernel(const unsigned short* __restrict__ xBC,
                                                   const float* __restrict__ csb,
                                                   const unsigned short* __restrict__ prevb,
                                                   const float* __restrict__ Dp,
                                                   const float* __restrict__ ypart,
                                                   unsigned short* __restrict__ yb) {
  int blk = blockIdx.x;
  int h = blk & 7, bc = blk >> 3;
  int c = bc & 63, b = bc >> 6;
  int tid = threadIdx.x, lane = tid & 63, wv = tid >> 6;
  int lr = lane & 15, lk = lane >> 4;
  int base = b * 4096 + c * 64;
  __shared__ float csc[64];
  if (tid < 64) csc[tid] = csb[(size_t)blk * 64 + tid];
  __syncthreads();

  float sc = expf(csc[wv * 16 + lr]);
  bf16x8_t ca[2];
  {
    size_t crow = (size_t)(base + wv * 16 + lr) * 1152 + 1088;
#pragma unroll
    for (int ks = 0; ks < 2; ++ks) {
      bf16x8_t v = *reinterpret_cast<const bf16x8_t*>(xBC + crow + ks * 32 + lk * 8);
      bf16x8_t d;
#pragma unroll
      for (int e = 0; e < 8; ++e) d[e] = (short)f2bf(bf2f((unsigned short)v[e]) * sc);
      ca[ks] = d;
    }
  }
  f32x4_t acc[8];
#pragma unroll
  for (int pf = 0; pf < 8; ++pf) acc[pf] = f32x4_t{0.f, 0.f, 0.f, 0.f};
#pragma unroll
  for (int ks = 0; ks < 2; ++ks) {
#pragma unroll
    for (int pf = 0; pf < 8; ++pf) {
      bf16x8_t pv = *reinterpret_cast<const bf16x8_t*>(
          prevb + (size_t)blk * 8192 + (size_t)(pf * 16 + lr) * 64 + ks * 32 + lk * 8);
      acc[pf] = __builtin_amdgcn_mfma_f32_16x16x32_bf16(ca[ks], pv, acc[pf], 0, 0, 0);
    }
  }
  float Dh = Dp[h];
#pragma unroll
  for (int pf = 0; pf < 8; ++pf)
#pragma unroll
    for (int r = 0; r < 4; ++r) {
      int i = wv * 16 + lk * 4 + r;
      size_t row = (size_t)(base + i);
      int p = pf * 16 + lr;
      float xr = bf2f(xBC[row * 1152 + h * 128 + p]);
      float yv = ypart[row * 1024 + h * 128 + p] + acc[pf][r] + Dh * xr;
      yb[row * 1024 + h * 128 + p] = f2bf(yv);
    }
}

// ---------------- RMSNorm over concat(y, z) bf16 -> bf16 ----------------
__global__ __launch_bounds__(256) void rmsnorm_kernel(const unsigned short* __restrict__ y,
                                                      const unsigned short* __restrict__ z,
                                                      const float* __restrict__ nw,
                                                      unsigned short* __restrict__ out) {
  int row = blockIdx.x, tid = threadIdx.x;
  ushort4 ya = reinterpret_cast<const ushort4*>(y + (size_t)row * 1024)[tid];
  ushort4 za = reinterpret_cast<const ushort4*>(z + (size_t)row * 1024)[tid];
  float yf[4] = {bf2f(ya.x), bf2f(ya.y), bf2f(ya.z), bf2f(ya.w)};
  float zf[4] = {bf2f(za.x), bf2f(za.y), bf2f(za.z), bf2f(za.w)};
  float ss = yf[0] * yf[0] + yf[1] * yf[1] + yf[2] * yf[2] + yf[3] * yf[3] +
             zf[0] * zf[0] + zf[1] * zf[1] + zf[2] * zf[2] + zf[3] * zf[3];
#pragma unroll
  for (int off = 32; off > 0; off >>= 1) ss += __shfl_down(ss, off, 64);
  __shared__ float red[4];
  __shared__ float stot;
  int lane = tid & 63, wv = tid >> 6;
  if (lane == 0) red[wv] = ss;
  __syncthreads();
  if (tid == 0) stot = rsqrtf((red[0] + red[1] + red[2] + red[3]) * (1.f / 2048.f) + 1e-5f);
  __syncthreads();
  float s = stot;
  float4 w1 = reinterpret_cast<const float4*>(nw)[tid];
  float4 w2 = reinterpret_cast<const float4*>(nw + 1024)[tid];
  ushort4 o1, o2;
  o1.x = f2bf(yf[0] * s * w1.x); o1.y = f2bf(yf[1] * s * w1.y);
  o1.z = f2bf(yf[2] * s * w1.z); o1.w = f2bf(yf[3] * s * w1.w);
  o2.x = f2bf(zf[0] * s * w2.x); o2.y = f2bf(zf[1] * s * w2.y);
  o2.z = f2bf(zf[2] * s * w2.z); o2.w = f2bf(zf[3] * s * w2.w);
  reinterpret_cast<ushort4*>(out + (size_t)row * 2048)[tid] = o1;
  reinterpret_cast<ushort4*>(out + (size_t)row * 2048 + 1024)[tid] = o2;
}

extern "C" void kernel_launch(void* const* d_in, const int* in_sizes, int n_in,
                              void* d_out, int out_size, void* d_ws, size_t ws_size,
                              hipStream_t stream) {
  const float* u       = (const float*)d_in[0];
  const float* W_in    = (const float*)d_in[1];
  const float* xconv_w = (const float*)d_in[2];
  const float* xconv_b = (const float*)d_in[3];
  const float* zconv_w = (const float*)d_in[4];
  const float* zconv_b = (const float*)d_in[5];
  const float* dt_bias = (const float*)d_in[6];
  const float* Alog    = (const float*)d_in[7];
  const float* Dp      = (const float*)d_in[8];
  const float* norm_w  = (const float*)d_in[9];
  const float* W_out   = (const float*)d_in[10];
  float* out = (float*)d_out;

  char* ws = (char*)d_ws;
  size_t o = 0;
  auto alc = [&](size_t bytes) { void* p = (void*)(ws + o); o = (o + bytes + 255) & ~(size_t)255; return p; };
  char* regA = (char*)alc(16777216);    // A1 (u bf16) -> yb (bf16)
  unsigned short* Wt1    = (unsigned short*)alc(4718592);   // W_in^T padded (2304 x 1024)
  unsigned short* Wt2    = (unsigned short*)alc(4194304);   // W_out^T (1024 x 2048)
  char* regZ = (char*)alc(37748736);    // zx (bf16 8192x2304) -> ypart (fp32 8192x1024)
  float*          dtv    = (float*)alc(262144);
  float*          csb    = (float*)alc(262144);
  unsigned short* xBC    = (unsigned short*)alc(18874368);  // 8192x1152 bf16
  unsigned short* zc     = (unsigned short*)alc(16777216);  // 8192x1024 bf16
  char* regS = (char*)alc(33554432);    // stat (bf16) -> normed (bf16 8192x2048)
  unsigned short* prevb  = (unsigned short*)alc(16777216);
  (void)ws_size; (void)in_sizes; (void)n_in; (void)out_size;

  unsigned short* A1     = (unsigned short*)regA;
  unsigned short* yb     = (unsigned short*)regA;
  unsigned short* zx     = (unsigned short*)regZ;
  float*          ypart  = (float*)regZ;
  unsigned short* stat   = (unsigned short*)regS;
  unsigned short* normed = (unsigned short*)regS;

  dim3 tb(32, 8);
  cvt_bf16_kernel<<<8192, 256, 0, stream>>>(u, A1, 2097152);
  transpose_bf16_kernel<<<dim3(72, 32), tb, 0, stream>>>(W_in, Wt1, 1024, 2176, 2184);
  transpose_bf16_kernel<<<dim3(32, 64), tb, 0, stream>>>(W_out, Wt2, 2048, 2048, 1024);
  gemm256_kernel<256, 1><<<288, 512, 0, stream>>>(A1, Wt1, (void*)zx, 1024, 2304, 32);
  dt_kernel<<<8192, 256, 0, stream>>>(u, W_in, dt_bias, dtv);
  conv_silu_tile_kernel<1152, 2304><<<576, 256, 0, stream>>>(zx + 1024, xconv_w, xconv_b, xBC);
  conv_silu_tile_kernel<1024, 2304><<<512, 256, 0, stream>>>(zx, zconv_w, zconv_b, zc);
  ssd1_kernel<<<1024, 256, 0, stream>>>(xBC, dtv, Alog, csb, stat, ypart);
  scan_kernel<<<512, 256, 0, stream>>>(stat, csb, prevb);
  ssd2_kernel<<<1024, 256, 0, stream>>>(xBC, csb, prevb, Dp, ypart, yb);
  rmsnorm_kernel<<<8192, 256, 0, stream>>>(yb, zc, norm_w, normed);
  gemm256_kernel<128, 0><<<256, 512, 0, stream>>>(normed, Wt2, (void*)out, 2048, 1024, 64);
}